// Round 1
// baseline (1100.706 us; speedup 1.0000x reference)
//
#include <hip/hip_runtime.h>

#define B_SZ 2048
#define IN_DIM 512
#define CTRL 512
#define N_LOC 65536
#define LOC_SZ 64
#define NSPLIT 32
#define LPS (N_LOC / NSPLIT)  // 2048 locations per split
#define EPSV 1e-8f

// ---------------- Kernel A: h = tanh(x @ W_h + b_h) ----------------
// grid (B/64, CTRL/64), block 256. 64x64 tile, 4x4 per-thread register tile.
__global__ __launch_bounds__(256) void k_hgemm(const float* __restrict__ x,
                                               const float* __restrict__ Wh,
                                               const float* __restrict__ bh,
                                               float* __restrict__ h) {
  __shared__ float xs[64][36];   // [row][k] k-step 32, pad 4 (16B-aligned rows)
  __shared__ float wls[32][68];  // [k][col] pad 4
  const int bm = blockIdx.x * 64, bn = blockIdx.y * 64;
  const int t = threadIdx.x;
  const int ti = t >> 4, tj = t & 15;
  float acc[4][4] = {};
  for (int k0 = 0; k0 < IN_DIM; k0 += 32) {
#pragma unroll
    for (int i = 0; i < 2; i++) {
      int lin = t + i * 256;          // float4 units, 512 total = 64x32 floats
      int r = lin >> 3, c4 = lin & 7;
      const float4 v = *(const float4*)&x[(size_t)(bm + r) * IN_DIM + k0 + c4 * 4];
      xs[r][c4 * 4 + 0] = v.x; xs[r][c4 * 4 + 1] = v.y;
      xs[r][c4 * 4 + 2] = v.z; xs[r][c4 * 4 + 3] = v.w;
    }
#pragma unroll
    for (int i = 0; i < 2; i++) {
      int lin = t + i * 256;          // 512 float4 = 32x64 floats
      int kk = lin >> 4, c4 = lin & 15;
      const float4 v = *(const float4*)&Wh[(size_t)(k0 + kk) * CTRL + bn + c4 * 4];
      wls[kk][c4 * 4 + 0] = v.x; wls[kk][c4 * 4 + 1] = v.y;
      wls[kk][c4 * 4 + 2] = v.z; wls[kk][c4 * 4 + 3] = v.w;
    }
    __syncthreads();
#pragma unroll 8
    for (int k = 0; k < 32; k++) {
      const float a0 = xs[4 * ti + 0][k], a1 = xs[4 * ti + 1][k];
      const float a2 = xs[4 * ti + 2][k], a3 = xs[4 * ti + 3][k];
      const float4 bv = *(const float4*)&wls[k][4 * tj];
      acc[0][0] += a0 * bv.x; acc[0][1] += a0 * bv.y; acc[0][2] += a0 * bv.z; acc[0][3] += a0 * bv.w;
      acc[1][0] += a1 * bv.x; acc[1][1] += a1 * bv.y; acc[1][2] += a1 * bv.z; acc[1][3] += a1 * bv.w;
      acc[2][0] += a2 * bv.x; acc[2][1] += a2 * bv.y; acc[2][2] += a2 * bv.z; acc[2][3] += a2 * bv.w;
      acc[3][0] += a3 * bv.x; acc[3][1] += a3 * bv.y; acc[3][2] += a3 * bv.z; acc[3][3] += a3 * bv.w;
    }
    __syncthreads();
  }
#pragma unroll
  for (int a = 0; a < 4; a++) {
    const int row = bm + 4 * ti + a;
    const int col = bn + 4 * tj;
    float4 o;
    o.x = tanhf(acc[a][0] + bh[col + 0]);
    o.y = tanhf(acc[a][1] + bh[col + 1]);
    o.z = tanhf(acc[a][2] + bh[col + 2]);
    o.w = tanhf(acc[a][3] + bh[col + 3]);
    *(float4*)&h[(size_t)row * CTRL + col] = o;
  }
}

// ---------------- Kernel B: h[-1] copy + gate[-1] ----------------
__global__ __launch_bounds__(512) void k_tail(const float* __restrict__ x,
                                              const float* __restrict__ Wg,
                                              const float* __restrict__ bg,
                                              const float* __restrict__ h,
                                              float* __restrict__ out) {
  __shared__ float red[8];
  const int t = threadIdx.x;
  out[2048 + t] = h[(size_t)(B_SZ - 1) * CTRL + t];
  float p = x[(size_t)(B_SZ - 1) * IN_DIM + t] * Wg[t];
#pragma unroll
  for (int off = 32; off >= 1; off >>= 1) p += __shfl_xor(p, off);
  if ((t & 63) == 0) red[t >> 6] = p;
  __syncthreads();
  if (t == 0) {
    float s = 0.f;
#pragma unroll
    for (int i = 0; i < 8; i++) s += red[i];
    out[2048 + 512] = s + bg[0];
  }
}

// ---------------- Kernel C: kn = normalize(tanh(h @ W_k + b_k)) ----------------
// block 256 = 4 waves, one wave per batch row. grid 512.
__global__ __launch_bounds__(256) void k_readkey(const float* __restrict__ h,
                                                 const float* __restrict__ Wk,
                                                 const float* __restrict__ bk,
                                                 float* __restrict__ kn) {
  const int lane = threadIdx.x & 63;
  const int row = blockIdx.x * 4 + (threadIdx.x >> 6);
  const float* hr = &h[(size_t)row * CTRL];
  float acc = 0.f;
  for (int k = 0; k < CTRL; k += 4) {
    const float4 hv = *(const float4*)&hr[k];
    acc += hv.x * Wk[(k + 0) * 64 + lane];
    acc += hv.y * Wk[(k + 1) * 64 + lane];
    acc += hv.z * Wk[(k + 2) * 64 + lane];
    acc += hv.w * Wk[(k + 3) * 64 + lane];
  }
  const float v = tanhf(acc + bk[lane]);
  float ss = v * v;
#pragma unroll
  for (int off = 32; off >= 1; off >>= 1) ss += __shfl_xor(ss, off);
  kn[(size_t)row * 64 + lane] = v / (sqrtf(ss) + EPSV);
}

// ---------------- Kernel D: inv_norm over memory rows ----------------
__global__ __launch_bounds__(256) void k_mnorm(const float* __restrict__ M,
                                               float* __restrict__ invn) {
  const int lane = threadIdx.x & 63;
  const int loc = blockIdx.x * 4 + (threadIdx.x >> 6);
  const float v = M[(size_t)loc * 64 + lane];
  float ss = v * v;
#pragma unroll
  for (int off = 32; off >= 1; off >>= 1) ss += __shfl_xor(ss, off);
  if (lane == 0) invn[loc] = 1.f / (sqrtf(ss) + EPSV);
}

// ---------------- Kernel E: fused attention partials ----------------
// grid (B/64, NSPLIT). Block: 64 rows x 2048 locs, 64-loc subtiles.
// Per-thread 4x4 register tiles for both S and R phases.
__global__ __launch_bounds__(256) void k_attn(const float* __restrict__ kn,
                                              const float* __restrict__ M,
                                              const float* __restrict__ invn,
                                              float* __restrict__ m_part,
                                              float* __restrict__ l_part,
                                              float* __restrict__ r_part) {
  __shared__ float kns[64][68];   // [row][k], pad 4
  __shared__ float Ms[64][64];    // [loc][d], XOR-swizzled float4 quads
  __shared__ float Ps[64][68];    // [row][loc], pad 4
  const int rb = blockIdx.x, sp = blockIdx.y;
  const int t = threadIdx.x;
  const int ti = t >> 4, tj = t & 15;
  const int row0 = rb * 64, loc0 = sp * LPS;

#pragma unroll
  for (int i = 0; i < 4; i++) {
    int lin = t + i * 256;          // 1024 float4 = 64x64 floats
    int r = lin >> 4, c4 = lin & 15;
    const float4 v = *(const float4*)&kn[(size_t)(row0 + r) * 64 + c4 * 4];
    kns[r][c4 * 4 + 0] = v.x; kns[r][c4 * 4 + 1] = v.y;
    kns[r][c4 * 4 + 2] = v.z; kns[r][c4 * 4 + 3] = v.w;
  }
  float R[4][4] = {};
  float mrow[4], lrow[4];
#pragma unroll
  for (int a = 0; a < 4; a++) { mrow[a] = -3.0e38f; lrow[a] = 0.f; }
  __syncthreads();

  for (int lt = 0; lt < LPS; lt += 64) {
    // stage M subtile with XOR swizzle: logical quad c4 at row r stored at c4 ^ ((r>>2)&15)
#pragma unroll
    for (int i = 0; i < 4; i++) {
      int lin = t + i * 256;
      int r = lin >> 4, c4 = lin & 15;
      const float4 v = *(const float4*)&M[(size_t)(loc0 + lt + r) * 64 + c4 * 4];
      *(float4*)&Ms[r][(c4 ^ ((r >> 2) & 15)) * 4] = v;
    }
    __syncthreads();

    // S[a][b] = dot(kn[4ti+a], M[4tj+b]) over 64 dims
    float s[4][4] = {};
#pragma unroll
    for (int k4 = 0; k4 < 16; k4++) {
      float4 av[4], bv[4];
#pragma unroll
      for (int a = 0; a < 4; a++) av[a] = *(const float4*)&kns[4 * ti + a][k4 * 4];
#pragma unroll
      for (int b = 0; b < 4; b++) {
        const int r = 4 * tj + b;
        bv[b] = *(const float4*)&Ms[r][(k4 ^ ((r >> 2) & 15)) * 4];
      }
#pragma unroll
      for (int a = 0; a < 4; a++)
#pragma unroll
        for (int b = 0; b < 4; b++)
          s[a][b] += av[a].x * bv[b].x + av[a].y * bv[b].y + av[a].z * bv[b].z + av[a].w * bv[b].w;
    }
    // fold cosine normalization of M rows
    float inv4[4];
#pragma unroll
    for (int b = 0; b < 4; b++) inv4[b] = invn[loc0 + lt + 4 * tj + b];
#pragma unroll
    for (int a = 0; a < 4; a++)
#pragma unroll
      for (int b = 0; b < 4; b++) s[a][b] *= inv4[b];

    // online softmax per row; 16 lanes (same ti) share a row group
#pragma unroll
    for (int a = 0; a < 4; a++) {
      float tm = fmaxf(fmaxf(s[a][0], s[a][1]), fmaxf(s[a][2], s[a][3]));
#pragma unroll
      for (int off = 1; off < 16; off <<= 1) tm = fmaxf(tm, __shfl_xor(tm, off));
      const float mn = fmaxf(mrow[a], tm);
      const float p0 = __expf(s[a][0] - mn), p1 = __expf(s[a][1] - mn);
      const float p2 = __expf(s[a][2] - mn), p3 = __expf(s[a][3] - mn);
      float rs = p0 + p1 + p2 + p3;
#pragma unroll
      for (int off = 1; off < 16; off <<= 1) rs += __shfl_xor(rs, off);
      const float sc = __expf(mrow[a] - mn);
      lrow[a] = lrow[a] * sc + rs;
      mrow[a] = mn;
#pragma unroll
      for (int b = 0; b < 4; b++) R[a][b] *= sc;
      *(float4*)&Ps[4 * ti + a][4 * tj] = make_float4(p0, p1, p2, p3);
    }
    __syncthreads();

    // R[rows 4ti+a][dims 4tj+b] += P @ Msub
#pragma unroll
    for (int l4 = 0; l4 < 16; l4++) {
      float4 pv[4], mv[4];
#pragma unroll
      for (int a = 0; a < 4; a++) pv[a] = *(const float4*)&Ps[4 * ti + a][l4 * 4];
#pragma unroll
      for (int c = 0; c < 4; c++) {
        const int loc = l4 * 4 + c;
        mv[c] = *(const float4*)&Ms[loc][(tj ^ ((loc >> 2) & 15)) * 4];
      }
#pragma unroll
      for (int a = 0; a < 4; a++) {
        R[a][0] += pv[a].x * mv[0].x + pv[a].y * mv[1].x + pv[a].z * mv[2].x + pv[a].w * mv[3].x;
        R[a][1] += pv[a].x * mv[0].y + pv[a].y * mv[1].y + pv[a].z * mv[2].y + pv[a].w * mv[3].y;
        R[a][2] += pv[a].x * mv[0].z + pv[a].y * mv[1].z + pv[a].z * mv[2].z + pv[a].w * mv[3].z;
        R[a][3] += pv[a].x * mv[0].w + pv[a].y * mv[1].w + pv[a].z * mv[2].w + pv[a].w * mv[3].w;
      }
    }
    __syncthreads();
  }

#pragma unroll
  for (int a = 0; a < 4; a++) {
    const int row = row0 + 4 * ti + a;
    if (tj == 0) {
      m_part[(size_t)row * NSPLIT + sp] = mrow[a];
      l_part[(size_t)row * NSPLIT + sp] = lrow[a];
    }
    *(float4*)&r_part[((size_t)row * NSPLIT + sp) * 64 + 4 * tj] =
        make_float4(R[a][0], R[a][1], R[a][2], R[a][3]);
  }
}

// ---------------- Kernel F: combine partials + output dot ----------------
// block 256 = 4 waves, one wave per batch row. grid 512.
__global__ __launch_bounds__(256) void k_combine(const float* __restrict__ m_part,
                                                 const float* __restrict__ l_part,
                                                 const float* __restrict__ r_part,
                                                 const float* __restrict__ h,
                                                 const float* __restrict__ Wout,
                                                 const float* __restrict__ bout,
                                                 float* __restrict__ out,
                                                 float* __restrict__ m_fin,
                                                 float* __restrict__ l_fin) {
  const int lane = threadIdx.x & 63;
  const int row = blockIdx.x * 4 + (threadIdx.x >> 6);
  const float mp = (lane < NSPLIT) ? m_part[(size_t)row * NSPLIT + lane] : -3.0e38f;
  float m = mp;
#pragma unroll
  for (int off = 32; off >= 1; off >>= 1) m = fmaxf(m, __shfl_xor(m, off));
  float l = (lane < NSPLIT) ? l_part[(size_t)row * NSPLIT + lane] * __expf(mp - m) : 0.f;
#pragma unroll
  for (int off = 32; off >= 1; off >>= 1) l += __shfl_xor(l, off);
  // r component d = lane
  float rd = 0.f;
  for (int sp2 = 0; sp2 < NSPLIT; sp2++) {
    const float msp = m_part[(size_t)row * NSPLIT + sp2];
    rd += r_part[((size_t)row * NSPLIT + sp2) * 64 + lane] * __expf(msp - m);
  }
  rd /= l;
  float acc = Wout[CTRL + lane] * rd;
  for (int k = lane; k < CTRL; k += 64) acc += h[(size_t)row * CTRL + k] * Wout[k];
#pragma unroll
  for (int off = 32; off >= 1; off >>= 1) acc += __shfl_xor(acc, off);
  if (lane == 0) {
    out[row] = acc + bout[0];
    m_fin[row] = m;
    l_fin[row] = l;
  }
}

// ---------------- Kernel G: w_read for row B-1 ----------------
__global__ __launch_bounds__(256) void k_wread(const float* __restrict__ kn,
                                               const float* __restrict__ M,
                                               const float* __restrict__ invn,
                                               const float* __restrict__ m_fin,
                                               const float* __restrict__ l_fin,
                                               float* __restrict__ out) {
  const int lane = threadIdx.x & 63;
  const int loc = blockIdx.x * 4 + (threadIdx.x >> 6);
  float v = kn[(size_t)(B_SZ - 1) * 64 + lane] * M[(size_t)loc * 64 + lane];
#pragma unroll
  for (int off = 32; off >= 1; off >>= 1) v += __shfl_xor(v, off);
  const float sim = v * invn[loc];
  const float w = __expf(sim - m_fin[B_SZ - 1]) / l_fin[B_SZ - 1];
  if (lane == 0) out[2048 + 512 + 1 + loc] = w;
}

extern "C" void kernel_launch(void* const* d_in, const int* in_sizes, int n_in,
                              void* d_out, int out_size, void* d_ws, size_t ws_size,
                              hipStream_t stream) {
  const float* x    = (const float*)d_in[0];
  const float* Wh   = (const float*)d_in[1];
  const float* bh   = (const float*)d_in[2];
  const float* Wg   = (const float*)d_in[3];
  const float* bg   = (const float*)d_in[4];
  const float* Wk   = (const float*)d_in[5];
  const float* bk   = (const float*)d_in[6];
  const float* M    = (const float*)d_in[7];
  const float* Wout = (const float*)d_in[8];
  const float* bout = (const float*)d_in[9];
  float* out = (float*)d_out;

  float* ws     = (float*)d_ws;
  float* h      = ws;                       // 2048*512   = 1,048,576
  float* kn     = h + 1048576;              // 2048*64    =   131,072
  float* invn   = kn + 131072;              // 65536
  float* m_part = invn + 65536;             // 2048*32    =    65,536
  float* l_part = m_part + 65536;           // 65,536
  float* r_part = l_part + 65536;           // 2048*32*64 = 4,194,304
  float* m_fin  = r_part + 4194304;         // 2048
  float* l_fin  = m_fin + 2048;             // 2048  (total ~21.3 MiB)

  hipLaunchKernelGGL(k_hgemm, dim3(B_SZ / 64, CTRL / 64), dim3(256), 0, stream, x, Wh, bh, h);
  hipLaunchKernelGGL(k_tail, dim3(1), dim3(512), 0, stream, x, Wg, bg, h, out);
  hipLaunchKernelGGL(k_readkey, dim3(B_SZ / 4), dim3(256), 0, stream, h, Wk, bk, kn);
  hipLaunchKernelGGL(k_mnorm, dim3(N_LOC / 4), dim3(256), 0, stream, M, invn);
  hipLaunchKernelGGL(k_attn, dim3(B_SZ / 64, NSPLIT), dim3(256), 0, stream,
                     kn, M, invn, m_part, l_part, r_part);
  hipLaunchKernelGGL(k_combine, dim3(B_SZ / 4), dim3(256), 0, stream,
                     m_part, l_part, r_part, h, Wout, bout, out, m_fin, l_fin);
  hipLaunchKernelGGL(k_wread, dim3(N_LOC / 4), dim3(256), 0, stream,
                     kn, M, invn, m_fin, l_fin, out);
}

// Round 2
// 209.162 us; speedup vs baseline: 5.2625x; 5.2625x over previous
//
#include <hip/hip_runtime.h>

#define B_SZ 2048
#define IN_DIM 512
#define CTRL 512
#define N_LOC 65536
#define LOC_SZ 64
#define NSPLIT 32
#define LPS (N_LOC / NSPLIT)  // 2048 locations per split
#define EPSV 1e-8f

typedef __attribute__((ext_vector_type(8))) short bf16x8;
typedef __attribute__((ext_vector_type(4))) float f32x4;
typedef __attribute__((ext_vector_type(4))) unsigned int u32x4;

static __device__ __forceinline__ unsigned short f2bf(float f) {
  unsigned int u = __builtin_bit_cast(unsigned int, f);
  unsigned int r = (u + 0x7fffu + ((u >> 16) & 1u)) >> 16;
  return (unsigned short)r;
}
static __device__ __forceinline__ float bf2f(unsigned short u) {
  return __builtin_bit_cast(float, ((unsigned int)u) << 16);
}

// ---------------- Kernel A: h = tanh(x @ W_h + b_h) ----------------
__global__ __launch_bounds__(256) void k_hgemm(const float* __restrict__ x,
                                               const float* __restrict__ Wh,
                                               const float* __restrict__ bh,
                                               float* __restrict__ h) {
  __shared__ float xs[64][36];
  __shared__ float wls[32][68];
  const int bm = blockIdx.x * 64, bn = blockIdx.y * 64;
  const int t = threadIdx.x;
  const int ti = t >> 4, tj = t & 15;
  float acc[4][4] = {};
  for (int k0 = 0; k0 < IN_DIM; k0 += 32) {
#pragma unroll
    for (int i = 0; i < 2; i++) {
      int lin = t + i * 256;
      int r = lin >> 3, c4 = lin & 7;
      const float4 v = *(const float4*)&x[(size_t)(bm + r) * IN_DIM + k0 + c4 * 4];
      xs[r][c4 * 4 + 0] = v.x; xs[r][c4 * 4 + 1] = v.y;
      xs[r][c4 * 4 + 2] = v.z; xs[r][c4 * 4 + 3] = v.w;
    }
#pragma unroll
    for (int i = 0; i < 2; i++) {
      int lin = t + i * 256;
      int kk = lin >> 4, c4 = lin & 15;
      const float4 v = *(const float4*)&Wh[(size_t)(k0 + kk) * CTRL + bn + c4 * 4];
      wls[kk][c4 * 4 + 0] = v.x; wls[kk][c4 * 4 + 1] = v.y;
      wls[kk][c4 * 4 + 2] = v.z; wls[kk][c4 * 4 + 3] = v.w;
    }
    __syncthreads();
#pragma unroll 8
    for (int k = 0; k < 32; k++) {
      const float a0 = xs[4 * ti + 0][k], a1 = xs[4 * ti + 1][k];
      const float a2 = xs[4 * ti + 2][k], a3 = xs[4 * ti + 3][k];
      const float4 bv = *(const float4*)&wls[k][4 * tj];
      acc[0][0] += a0 * bv.x; acc[0][1] += a0 * bv.y; acc[0][2] += a0 * bv.z; acc[0][3] += a0 * bv.w;
      acc[1][0] += a1 * bv.x; acc[1][1] += a1 * bv.y; acc[1][2] += a1 * bv.z; acc[1][3] += a1 * bv.w;
      acc[2][0] += a2 * bv.x; acc[2][1] += a2 * bv.y; acc[2][2] += a2 * bv.z; acc[2][3] += a2 * bv.w;
      acc[3][0] += a3 * bv.x; acc[3][1] += a3 * bv.y; acc[3][2] += a3 * bv.z; acc[3][3] += a3 * bv.w;
    }
    __syncthreads();
  }
#pragma unroll
  for (int a = 0; a < 4; a++) {
    const int row = bm + 4 * ti + a;
    const int col = bn + 4 * tj;
    float4 o;
    o.x = tanhf(acc[a][0] + bh[col + 0]);
    o.y = tanhf(acc[a][1] + bh[col + 1]);
    o.z = tanhf(acc[a][2] + bh[col + 2]);
    o.w = tanhf(acc[a][3] + bh[col + 3]);
    *(float4*)&h[(size_t)row * CTRL + col] = o;
  }
}

// ---------------- Kernel B: h[-1] copy + gate[-1] ----------------
__global__ __launch_bounds__(512) void k_tail(const float* __restrict__ x,
                                              const float* __restrict__ Wg,
                                              const float* __restrict__ bg,
                                              const float* __restrict__ h,
                                              float* __restrict__ out) {
  __shared__ float red[8];
  const int t = threadIdx.x;
  out[2048 + t] = h[(size_t)(B_SZ - 1) * CTRL + t];
  float p = x[(size_t)(B_SZ - 1) * IN_DIM + t] * Wg[t];
#pragma unroll
  for (int off = 32; off >= 1; off >>= 1) p += __shfl_xor(p, off);
  if ((t & 63) == 0) red[t >> 6] = p;
  __syncthreads();
  if (t == 0) {
    float s = 0.f;
#pragma unroll
    for (int i = 0; i < 8; i++) s += red[i];
    out[2048 + 512] = s + bg[0];
  }
}

// ---------------- Kernel C: kn = normalize(tanh(h @ W_k + b_k)) -> bf16 ----------------
__global__ __launch_bounds__(256) void k_readkey(const float* __restrict__ h,
                                                 const float* __restrict__ Wk,
                                                 const float* __restrict__ bk,
                                                 unsigned short* __restrict__ kn_bf) {
  const int lane = threadIdx.x & 63;
  const int row = blockIdx.x * 4 + (threadIdx.x >> 6);
  const float* hr = &h[(size_t)row * CTRL];
  float acc = 0.f;
  for (int k = 0; k < CTRL; k += 4) {
    const float4 hv = *(const float4*)&hr[k];
    acc += hv.x * Wk[(k + 0) * 64 + lane];
    acc += hv.y * Wk[(k + 1) * 64 + lane];
    acc += hv.z * Wk[(k + 2) * 64 + lane];
    acc += hv.w * Wk[(k + 3) * 64 + lane];
  }
  const float v = tanhf(acc + bk[lane]);
  float ss = v * v;
#pragma unroll
  for (int off = 32; off >= 1; off >>= 1) ss += __shfl_xor(ss, off);
  kn_bf[(size_t)row * 64 + lane] = f2bf(v / (sqrtf(ss) + EPSV));
}

// ---------------- Kernel D: inv_norm over memory rows ----------------
__global__ __launch_bounds__(256) void k_mnorm(const float* __restrict__ M,
                                               float* __restrict__ invn) {
  const int lane = threadIdx.x & 63;
  const int loc = blockIdx.x * 4 + (threadIdx.x >> 6);
  const float v = M[(size_t)loc * 64 + lane];
  float ss = v * v;
#pragma unroll
  for (int off = 32; off >= 1; off >>= 1) ss += __shfl_xor(ss, off);
  if (lane == 0) invn[loc] = 1.f / (sqrtf(ss) + EPSV);
}

// ---------------- Kernel D2: build bf16 tiled copies of M ----------------
// Mn_t: [1024 tiles][64 loc][64 d], normalized (invn folded), bf16
// Mt_t: [1024 tiles][64 d][64 loc], raw, bf16
__global__ __launch_bounds__(256) void k_prep(const float* __restrict__ M,
                                              const float* __restrict__ invn,
                                              unsigned short* __restrict__ Mn_t,
                                              unsigned short* __restrict__ Mt_t) {
  const int b = blockIdx.x;  // tile over 64 locations
  const int t = threadIdx.x;
  const int c4 = t & 15, lg = t >> 4;
  float vv[4][4];
  float iv[4];
#pragma unroll
  for (int r = 0; r < 4; r++) {
    const int loc = b * 64 + lg * 4 + r;
    const float4 f = *(const float4*)&M[(size_t)loc * 64 + c4 * 4];
    vv[r][0] = f.x; vv[r][1] = f.y; vv[r][2] = f.z; vv[r][3] = f.w;
    iv[r] = invn[loc];
  }
#pragma unroll
  for (int r = 0; r < 4; r++) {
    ushort4 o = make_ushort4(f2bf(vv[r][0] * iv[r]), f2bf(vv[r][1] * iv[r]),
                             f2bf(vv[r][2] * iv[r]), f2bf(vv[r][3] * iv[r]));
    *(ushort4*)&Mn_t[(size_t)b * 4096 + (lg * 4 + r) * 64 + c4 * 4] = o;
  }
#pragma unroll
  for (int j = 0; j < 4; j++) {
    ushort4 o = make_ushort4(f2bf(vv[0][j]), f2bf(vv[1][j]), f2bf(vv[2][j]), f2bf(vv[3][j]));
    *(ushort4*)&Mt_t[(size_t)b * 4096 + (c4 * 4 + j) * 64 + lg * 4] = o;
  }
}

// ---------------- Kernel E: fused attention partials (MFMA bf16) ----------------
// grid (B/64, NSPLIT), block 256 = 4 waves; wave w owns batch rows 16w..16w+15.
// Per 64-loc subtile: S^T = mfma(A=Mn tile, B=kn tile) -> online softmax in regs
// -> P A-frags rebuilt via shfl -> R += mfma(A=P, B=Mt tile).
__global__ __launch_bounds__(256, 4) void k_attn(const unsigned short* __restrict__ kn_bf,
                                                 const unsigned short* __restrict__ Mn_t,
                                                 const unsigned short* __restrict__ Mt_t,
                                                 float* __restrict__ m_part,
                                                 float* __restrict__ l_part,
                                                 float* __restrict__ r_part) {
  __shared__ __align__(16) unsigned short kns[4096];
  __shared__ __align__(16) unsigned short Mrow[4096];
  __shared__ __align__(16) unsigned short Mt[4096];
  const int rb = blockIdx.x, sp = blockIdx.y;
  const int t = threadIdx.x;
  const int lane = t & 63, w = t >> 6;
  const int lo = lane & 15, g = lane >> 4;
  const int row0 = rb * 64;

  // stage kn rows (swizzled: ushort idx d ^ ((row&7)*8), 16B units)
#pragma unroll
  for (int i = 0; i < 4; i++) {
    int c = t + i * 256;
    int r = c >> 4, c8 = c & 15;
    *(ushort4*)&kns[r * 64 + ((c8 * 4) ^ ((r & 7) * 8))] =
        *(const ushort4*)&kn_bf[(size_t)(row0 + r) * 64 + c8 * 4];
  }

  f32x4 Racc[4];
#pragma unroll
  for (int dt = 0; dt < 4; dt++) Racc[dt] = (f32x4){0.f, 0.f, 0.f, 0.f};
  float mrun = -3.0e38f, lrun = 0.f;

  for (int it = 0; it < LPS / 64; ++it) {
    const size_t tb = ((size_t)(sp * (LPS / 64) + it)) * 4096;
#pragma unroll
    for (int i = 0; i < 4; i++) {
      int c = t + i * 256;
      int r = c >> 4, c8 = c & 15;
      const int di = r * 64 + ((c8 * 4) ^ ((r & 7) * 8));
      *(ushort4*)&Mrow[di] = *(const ushort4*)&Mn_t[tb + c * 4];
      *(ushort4*)&Mt[di] = *(const ushort4*)&Mt_t[tb + c * 4];
    }
    __syncthreads();

    // ---- phase 1: S^T[loc][row] ----
    f32x4 cst[4];
#pragma unroll
    for (int lt = 0; lt < 4; lt++) cst[lt] = (f32x4){0.f, 0.f, 0.f, 0.f};
#pragma unroll
    for (int kk = 0; kk < 2; kk++) {
      const int koff = (32 * kk + 8 * g) ^ ((lo & 7) * 8);
      const bf16x8 bfr = *(const bf16x8*)&kns[(16 * w + lo) * 64 + koff];
#pragma unroll
      for (int lt = 0; lt < 4; lt++) {
        const bf16x8 afr = *(const bf16x8*)&Mrow[(16 * lt + lo) * 64 + koff];
        cst[lt] = __builtin_amdgcn_mfma_f32_16x16x32_bf16(afr, bfr, cst[lt], 0, 0, 0);
      }
    }

    // ---- online softmax (row = lo per lane) ----
    float tm = -3.0e38f;
#pragma unroll
    for (int lt = 0; lt < 4; lt++)
      tm = fmaxf(tm, fmaxf(fmaxf(cst[lt][0], cst[lt][1]), fmaxf(cst[lt][2], cst[lt][3])));
    tm = fmaxf(tm, __shfl_xor(tm, 16));
    tm = fmaxf(tm, __shfl_xor(tm, 32));
    const float mn = fmaxf(mrun, tm);
    const float sc = __expf(mrun - mn);
    mrun = mn;
    float p[16];
    float ls = 0.f;
#pragma unroll
    for (int lt = 0; lt < 4; lt++)
#pragma unroll
      for (int q = 0; q < 4; q++) {
        const float e = __expf(cst[lt][q] - mn);
        p[lt * 4 + q] = e;
        ls += e;
      }
    ls += __shfl_xor(ls, 16);
    ls += __shfl_xor(ls, 32);
    lrun = lrun * sc + ls;
    // rescale R (lane's R rows are 4g+q; row state lives at lane (4g+q))
    float scq[4];
#pragma unroll
    for (int q = 0; q < 4; q++) scq[q] = __shfl(sc, 4 * g + q);
#pragma unroll
    for (int dt = 0; dt < 4; dt++)
#pragma unroll
      for (int q = 0; q < 4; q++) Racc[dt][q] *= scq[q];

    // pack P to bf16 pairs: pk[lt*2+wi] = (p[lt][2wi], p[lt][2wi+1])
    unsigned int pk[8];
#pragma unroll
    for (int lt = 0; lt < 4; lt++) {
      pk[lt * 2 + 0] = (unsigned int)f2bf(p[lt * 4 + 0]) | ((unsigned int)f2bf(p[lt * 4 + 1]) << 16);
      pk[lt * 2 + 1] = (unsigned int)f2bf(p[lt * 4 + 2]) | ((unsigned int)f2bf(p[lt * 4 + 3]) << 16);
    }

    // ---- phase 2: R[row][d] += P @ Mt ----
#pragma unroll
    for (int kk = 0; kk < 2; kk++) {
      unsigned int aw[4];
#pragma unroll
      for (int wd = 0; wd < 4; wd++) {
        const int srcl = lo + 16 * (2 * (g & 1) + (wd >> 1));
        const unsigned int a0 = __shfl(pk[(2 * kk) * 2 + (wd & 1)], srcl);
        const unsigned int a1 = __shfl(pk[(2 * kk + 1) * 2 + (wd & 1)], srcl);
        aw[wd] = (g & 2) ? a1 : a0;
      }
      const u32x4 awv = {aw[0], aw[1], aw[2], aw[3]};
      const bf16x8 afr = __builtin_bit_cast(bf16x8, awv);
#pragma unroll
      for (int dt = 0; dt < 4; dt++) {
        const bf16x8 bfr =
            *(const bf16x8*)&Mt[(16 * dt + lo) * 64 + ((32 * kk + 8 * g) ^ ((lo & 7) * 8))];
        Racc[dt] = __builtin_amdgcn_mfma_f32_16x16x32_bf16(afr, bfr, Racc[dt], 0, 0, 0);
      }
    }
    __syncthreads();
  }

  if (g == 0) {
    const int row = row0 + 16 * w + lo;
    m_part[(size_t)row * NSPLIT + sp] = mrun;
    l_part[(size_t)row * NSPLIT + sp] = lrun;
  }
#pragma unroll
  for (int dt = 0; dt < 4; dt++)
#pragma unroll
    for (int q = 0; q < 4; q++) {
      const int row = row0 + 16 * w + 4 * g + q;
      r_part[((size_t)row * NSPLIT + sp) * 64 + 16 * dt + lo] = Racc[dt][q];
    }
}

// ---------------- Kernel F: combine partials + output dot ----------------
__global__ __launch_bounds__(256) void k_combine(const float* __restrict__ m_part,
                                                 const float* __restrict__ l_part,
                                                 const float* __restrict__ r_part,
                                                 const float* __restrict__ h,
                                                 const float* __restrict__ Wout,
                                                 const float* __restrict__ bout,
                                                 float* __restrict__ out,
                                                 float* __restrict__ m_fin,
                                                 float* __restrict__ l_fin) {
  const int lane = threadIdx.x & 63;
  const int row = blockIdx.x * 4 + (threadIdx.x >> 6);
  const float mp = (lane < NSPLIT) ? m_part[(size_t)row * NSPLIT + lane] : -3.0e38f;
  float m = mp;
#pragma unroll
  for (int off = 32; off >= 1; off >>= 1) m = fmaxf(m, __shfl_xor(m, off));
  float l = (lane < NSPLIT) ? l_part[(size_t)row * NSPLIT + lane] * __expf(mp - m) : 0.f;
#pragma unroll
  for (int off = 32; off >= 1; off >>= 1) l += __shfl_xor(l, off);
  float rd = 0.f;
  for (int sp2 = 0; sp2 < NSPLIT; sp2++) {
    const float msp = m_part[(size_t)row * NSPLIT + sp2];
    rd += r_part[((size_t)row * NSPLIT + sp2) * 64 + lane] * __expf(msp - m);
  }
  rd /= l;
  float acc = Wout[CTRL + lane] * rd;
  for (int k = lane; k < CTRL; k += 64) acc += h[(size_t)row * CTRL + k] * Wout[k];
#pragma unroll
  for (int off = 32; off >= 1; off >>= 1) acc += __shfl_xor(acc, off);
  if (lane == 0) {
    out[row] = acc + bout[0];
    m_fin[row] = m;
    l_fin[row] = l;
  }
}

// ---------------- Kernel G: w_read for row B-1 ----------------
__global__ __launch_bounds__(256) void k_wread(const unsigned short* __restrict__ kn_bf,
                                               const float* __restrict__ M,
                                               const float* __restrict__ invn,
                                               const float* __restrict__ m_fin,
                                               const float* __restrict__ l_fin,
                                               float* __restrict__ out) {
  const int lane = threadIdx.x & 63;
  const int loc = blockIdx.x * 4 + (threadIdx.x >> 6);
  float v = bf2f(kn_bf[(size_t)(B_SZ - 1) * 64 + lane]) * M[(size_t)loc * 64 + lane];
#pragma unroll
  for (int off = 32; off >= 1; off >>= 1) v += __shfl_xor(v, off);
  const float sim = v * invn[loc];
  const float wv = __expf(sim - m_fin[B_SZ - 1]) / l_fin[B_SZ - 1];
  if (lane == 0) out[2048 + 512 + 1 + loc] = wv;
}

extern "C" void kernel_launch(void* const* d_in, const int* in_sizes, int n_in,
                              void* d_out, int out_size, void* d_ws, size_t ws_size,
                              hipStream_t stream) {
  const float* x = (const float*)d_in[0];
  const float* Wh = (const float*)d_in[1];
  const float* bh = (const float*)d_in[2];
  const float* Wg = (const float*)d_in[3];
  const float* bg = (const float*)d_in[4];
  const float* Wk = (const float*)d_in[5];
  const float* bk = (const float*)d_in[6];
  const float* M = (const float*)d_in[7];
  const float* Wout = (const float*)d_in[8];
  const float* bout = (const float*)d_in[9];
  float* out = (float*)d_out;

  float* ws = (float*)d_ws;
  float* h = ws;                             // 1,048,576 f
  float* invn = h + 1048576;                 // 65,536 f
  float* m_part = invn + 65536;              // 65,536 f
  float* l_part = m_part + 65536;            // 65,536 f
  float* r_part = l_part + 65536;            // 4,194,304 f
  float* m_fin = r_part + 4194304;           // 2,048 f
  float* l_fin = m_fin + 2048;               // 2,048 f
  unsigned short* kn_bf = (unsigned short*)(l_fin + 2048);      // 131,072 us (= 65,536 f)
  unsigned short* Mn_t = (unsigned short*)((float*)kn_bf + 65536);  // 4,194,304 us (8 MB)
  unsigned short* Mt_t = Mn_t + 4194304;                            // 4,194,304 us (8 MB)
  // total ~39.1 MB

  hipLaunchKernelGGL(k_hgemm, dim3(B_SZ / 64, CTRL / 64), dim3(256), 0, stream, x, Wh, bh, h);
  hipLaunchKernelGGL(k_tail, dim3(1), dim3(512), 0, stream, x, Wg, bg, h, out);
  hipLaunchKernelGGL(k_readkey, dim3(B_SZ / 4), dim3(256), 0, stream, h, Wk, bk, kn_bf);
  hipLaunchKernelGGL(k_mnorm, dim3(N_LOC / 4), dim3(256), 0, stream, M, invn);
  hipLaunchKernelGGL(k_prep, dim3(N_LOC / 64), dim3(256), 0, stream, M, invn, Mn_t, Mt_t);
  hipLaunchKernelGGL(k_attn, dim3(B_SZ / 64, NSPLIT), dim3(256), 0, stream,
                     kn_bf, Mn_t, Mt_t, m_part, l_part, r_part);
  hipLaunchKernelGGL(k_combine, dim3(B_SZ / 4), dim3(256), 0, stream,
                     m_part, l_part, r_part, h, Wout, bout, out, m_fin, l_fin);
  hipLaunchKernelGGL(k_wread, dim3(N_LOC / 4), dim3(256), 0, stream,
                     kn_bf, M, invn, m_fin, l_fin, out);
}

// Round 3
// 163.773 us; speedup vs baseline: 6.7209x; 1.2771x over previous
//
#include <hip/hip_runtime.h>

#define B_SZ 2048
#define IN_DIM 512
#define CTRL 512
#define N_LOC 65536
#define LOC_SZ 64
#define NSPLIT 32
#define LPS (N_LOC / NSPLIT)
#define EPSV 1e-8f
#define LOG2E 1.4426950408889634f

typedef __attribute__((ext_vector_type(8))) short bf16x8;
typedef __attribute__((ext_vector_type(4))) float f32x4;
typedef __attribute__((ext_vector_type(4))) unsigned int u32x4;
typedef __attribute__((ext_vector_type(8))) unsigned short u16x8;

static __device__ __forceinline__ unsigned int cvtpk(float lo, float hi) {
  unsigned int r;
  asm("v_cvt_pk_bf16_f32 %0, %1, %2" : "=v"(r) : "v"(lo), "v"(hi));
  return r;
}
static __device__ __forceinline__ unsigned short f2bf_hw(float f) {
  return (unsigned short)(cvtpk(f, f) & 0xffffu);
}
static __device__ __forceinline__ float bf2f(unsigned short u) {
  return __builtin_bit_cast(float, ((unsigned int)u) << 16);
}
static __device__ __forceinline__ float exp2_fast(float x) {
  float r;
  asm("v_exp_f32 %0, %1" : "=v"(r) : "v"(x));
  return r;
}

// ---------------- Kernel A: h = tanh(x @ W_h + b_h), bf16 MFMA ----------------
// grid (32, 8), block 256 = 4 waves; wave w owns batch rows 16w..16w+15.
__global__ __launch_bounds__(256) void k_hgemm(const float* __restrict__ x,
                                               const float* __restrict__ Wh,
                                               const float* __restrict__ bh,
                                               float* __restrict__ h) {
  __shared__ __align__(16) unsigned short xs[64 * 40];  // [row][k], pad 40
  __shared__ __align__(16) unsigned short ws[64 * 40];  // [col][k], pad 40
  const int t = threadIdx.x, lane = t & 63, w = t >> 6, lo = lane & 15, g = lane >> 4;
  const int bm = blockIdx.x * 64, bn = blockIdx.y * 64;
  f32x4 acc[4];
#pragma unroll
  for (int ct = 0; ct < 4; ct++) acc[ct] = (f32x4){0.f, 0.f, 0.f, 0.f};

  for (int k0 = 0; k0 < IN_DIM; k0 += 32) {
    // stage x tile 64x32 -> bf16
#pragma unroll
    for (int i = 0; i < 2; i++) {
      const int lin = t + i * 256;
      const int r = lin >> 3, q = lin & 7;
      const float4 v = *(const float4*)&x[(size_t)(bm + r) * IN_DIM + k0 + q * 4];
      uint2 u;
      u.x = cvtpk(v.x, v.y);
      u.y = cvtpk(v.z, v.w);
      *(uint2*)&xs[r * 40 + q * 4] = u;
    }
    // stage Wh tile 32x64 transposed -> ws[col][k]
#pragma unroll
    for (int i = 0; i < 2; i++) {
      const int lin = t + i * 256;
      const int kk = lin >> 4, q = lin & 15;
      const float4 v = *(const float4*)&Wh[(size_t)(k0 + kk) * CTRL + bn + q * 4];
      const unsigned int a = cvtpk(v.x, v.y), b = cvtpk(v.z, v.w);
      ws[(q * 4 + 0) * 40 + kk] = (unsigned short)a;
      ws[(q * 4 + 1) * 40 + kk] = (unsigned short)(a >> 16);
      ws[(q * 4 + 2) * 40 + kk] = (unsigned short)b;
      ws[(q * 4 + 3) * 40 + kk] = (unsigned short)(b >> 16);
    }
    __syncthreads();
    const bf16x8 afr = *(const bf16x8*)&xs[(16 * w + lo) * 40 + 8 * g];
#pragma unroll
    for (int ct = 0; ct < 4; ct++) {
      const bf16x8 bfr = *(const bf16x8*)&ws[(16 * ct + lo) * 40 + 8 * g];
      acc[ct] = __builtin_amdgcn_mfma_f32_16x16x32_bf16(afr, bfr, acc[ct], 0, 0, 0);
    }
    __syncthreads();
  }
#pragma unroll
  for (int ct = 0; ct < 4; ct++)
#pragma unroll
    for (int q = 0; q < 4; q++) {
      const int row = bm + 16 * w + 4 * g + q;
      const int col = bn + 16 * ct + lo;
      h[(size_t)row * CTRL + col] = tanhf(acc[ct][q] + bh[col]);
    }
}

// ---------------- Kernel C: read-key (+ tail block) ----------------
// blocks 0..511: 4 waves, one wave per batch row. block 512: h[-1] copy + gate.
__global__ __launch_bounds__(256) void k_readkey(const float* __restrict__ h,
                                                 const float* __restrict__ Wk,
                                                 const float* __restrict__ bk,
                                                 const float* __restrict__ x,
                                                 const float* __restrict__ Wg,
                                                 const float* __restrict__ bg,
                                                 unsigned short* __restrict__ kn_bf,
                                                 float* __restrict__ out) {
  __shared__ float red[4];
  if (blockIdx.x < 512) {
    const int lane = threadIdx.x & 63;
    const int row = blockIdx.x * 4 + (threadIdx.x >> 6);
    const float* hr = &h[(size_t)row * CTRL];
    float acc = 0.f;
    for (int k = 0; k < CTRL; k += 4) {
      const float4 hv = *(const float4*)&hr[k];
      acc += hv.x * Wk[(k + 0) * 64 + lane];
      acc += hv.y * Wk[(k + 1) * 64 + lane];
      acc += hv.z * Wk[(k + 2) * 64 + lane];
      acc += hv.w * Wk[(k + 3) * 64 + lane];
    }
    const float v = tanhf(acc + bk[lane]);
    float ss = v * v;
#pragma unroll
    for (int off = 32; off >= 1; off >>= 1) ss += __shfl_xor(ss, off);
    kn_bf[(size_t)row * 64 + lane] = f2bf_hw(v / (sqrtf(ss) + EPSV));
  } else {
    const int t = threadIdx.x;
    out[2048 + t] = h[(size_t)(B_SZ - 1) * CTRL + t];
    out[2048 + 256 + t] = h[(size_t)(B_SZ - 1) * CTRL + 256 + t];
    float p = x[(size_t)(B_SZ - 1) * IN_DIM + t] * Wg[t] +
              x[(size_t)(B_SZ - 1) * IN_DIM + 256 + t] * Wg[256 + t];
#pragma unroll
    for (int off = 32; off >= 1; off >>= 1) p += __shfl_xor(p, off);
    if ((t & 63) == 0) red[t >> 6] = p;
    __syncthreads();
    if (t == 0) out[2048 + 512] = red[0] + red[1] + red[2] + red[3] + bg[0];
  }
}

// ---------------- Kernel D: norms + bf16 tiled copies of M ----------------
// Mn_t: [1024][64 loc][64 d], normalized * LOG2E. Mt_t: [1024][64 d][64 loc], raw.
__global__ __launch_bounds__(256) void k_prep(const float* __restrict__ M,
                                              float* __restrict__ invn,
                                              unsigned short* __restrict__ Mn_t,
                                              unsigned short* __restrict__ Mt_t) {
  const int b = blockIdx.x, t = threadIdx.x;
  const int c4 = t & 15, lg = t >> 4;
  float vv[4][4], ss[4];
#pragma unroll
  for (int r = 0; r < 4; r++) {
    const int loc = b * 64 + lg * 4 + r;
    const float4 f = *(const float4*)&M[(size_t)loc * 64 + c4 * 4];
    vv[r][0] = f.x; vv[r][1] = f.y; vv[r][2] = f.z; vv[r][3] = f.w;
    ss[r] = f.x * f.x + f.y * f.y + f.z * f.z + f.w * f.w;
  }
#pragma unroll
  for (int r = 0; r < 4; r++)
#pragma unroll
    for (int off = 1; off < 16; off <<= 1) ss[r] += __shfl_xor(ss[r], off);
  float inv[4];
#pragma unroll
  for (int r = 0; r < 4; r++) inv[r] = 1.f / (sqrtf(ss[r]) + EPSV);
  if (c4 == 0) {
#pragma unroll
    for (int r = 0; r < 4; r++) invn[b * 64 + lg * 4 + r] = inv[r];
  }
#pragma unroll
  for (int r = 0; r < 4; r++) {
    const float s = inv[r] * LOG2E;
    uint2 u;
    u.x = cvtpk(vv[r][0] * s, vv[r][1] * s);
    u.y = cvtpk(vv[r][2] * s, vv[r][3] * s);
    *(uint2*)&Mn_t[(size_t)b * 4096 + (lg * 4 + r) * 64 + c4 * 4] = u;
  }
#pragma unroll
  for (int j = 0; j < 4; j++) {
    uint2 u;
    u.x = cvtpk(vv[0][j], vv[1][j]);
    u.y = cvtpk(vv[2][j], vv[3][j]);
    *(uint2*)&Mt_t[(size_t)b * 4096 + (c4 * 4 + j) * 64 + lg * 4] = u;
  }
}

// ---------------- Kernel E: fused attention partials (MFMA, log2-domain) ----------------
// grid (32, NSPLIT), block 256 = 4 waves. Double-buffered LDS, reg prefetch,
// one barrier/iter, defer-max, hw cvt_pk, exp2-domain softmax.
__global__ __launch_bounds__(256, 4) void k_attn(const unsigned short* __restrict__ kn_bf,
                                                 const unsigned short* __restrict__ Mn_t,
                                                 const unsigned short* __restrict__ Mt_t,
                                                 float* __restrict__ m_part,
                                                 float* __restrict__ l_part,
                                                 float* __restrict__ r_part) {
  __shared__ __align__(16) unsigned short sKn[4096];
  __shared__ __align__(16) unsigned short sMn[2][4096];
  __shared__ __align__(16) unsigned short sMt[2][4096];
  const int rb = blockIdx.x, sp = blockIdx.y;
  const int t = threadIdx.x, lane = t & 63, w = t >> 6, lo = lane & 15, g = lane >> 4;
  const int row0 = rb * 64;

  // staging geometry: chunk c covers ushorts c*8..c*8+7; dest row r=c>>3, col=(c&7)*8
  const int c0 = t, c1 = t + 256;
  const int r0 = c0 >> 3, d0 = r0 * 64 + ((((c0 & 7) * 8)) ^ ((r0 & 7) * 8));
  const int r1 = c1 >> 3, d1 = r1 * 64 + ((((c1 & 7) * 8)) ^ ((r1 & 7) * 8));

  *(u16x8*)&sKn[d0] = *(const u16x8*)&kn_bf[(size_t)row0 * 64 + c0 * 8];
  *(u16x8*)&sKn[d1] = *(const u16x8*)&kn_bf[(size_t)row0 * 64 + c1 * 8];

  size_t gb = (size_t)(sp * 32) * 4096;
  u16x8 rn0 = *(const u16x8*)&Mn_t[gb + c0 * 8];
  u16x8 rn1 = *(const u16x8*)&Mn_t[gb + c1 * 8];
  u16x8 rt0 = *(const u16x8*)&Mt_t[gb + c0 * 8];
  u16x8 rt1 = *(const u16x8*)&Mt_t[gb + c1 * 8];
  *(u16x8*)&sMn[0][d0] = rn0; *(u16x8*)&sMn[0][d1] = rn1;
  *(u16x8*)&sMt[0][d0] = rt0; *(u16x8*)&sMt[0][d1] = rt1;
  __syncthreads();

  f32x4 Racc[4];
#pragma unroll
  for (int dt = 0; dt < 4; dt++) Racc[dt] = (f32x4){0.f, 0.f, 0.f, 0.f};
  float mrun = -3.0e38f, lrun = 0.f;

  for (int it = 0; it < 32; ++it) {
    const int cur = it & 1;
    // prefetch next tile into regs (hidden under compute)
    if (it < 31) {
      const size_t gn = (size_t)(sp * 32 + it + 1) * 4096;
      rn0 = *(const u16x8*)&Mn_t[gn + c0 * 8];
      rn1 = *(const u16x8*)&Mn_t[gn + c1 * 8];
      rt0 = *(const u16x8*)&Mt_t[gn + c0 * 8];
      rt1 = *(const u16x8*)&Mt_t[gn + c1 * 8];
    }

    // ---- phase 1: S^T = Mn_tile . kn^T ----
    f32x4 cst[4];
#pragma unroll
    for (int lt = 0; lt < 4; lt++) cst[lt] = (f32x4){0.f, 0.f, 0.f, 0.f};
#pragma unroll
    for (int kk = 0; kk < 2; kk++) {
      const int koff = (32 * kk + 8 * g) ^ ((lo & 7) * 8);
      const bf16x8 bfr = *(const bf16x8*)&sKn[(16 * w + lo) * 64 + koff];
#pragma unroll
      for (int lt = 0; lt < 4; lt++) {
        const bf16x8 afr = *(const bf16x8*)&sMn[cur][(16 * lt + lo) * 64 + koff];
        cst[lt] = __builtin_amdgcn_mfma_f32_16x16x32_bf16(afr, bfr, cst[lt], 0, 0, 0);
      }
    }

    // ---- online softmax (log2 domain), defer-max THR=8 ----
    float tm = cst[0][0];
#pragma unroll
    for (int lt = 0; lt < 4; lt++)
#pragma unroll
      for (int q = 0; q < 4; q++) tm = fmaxf(tm, cst[lt][q]);
    tm = fmaxf(tm, __shfl_xor(tm, 16));
    tm = fmaxf(tm, __shfl_xor(tm, 32));
    if (__any(tm > mrun + 8.f)) {
      const float mn = fmaxf(mrun, tm);
      const float sc = exp2_fast(mrun - mn);
      mrun = mn;
      lrun *= sc;
      float scq[4];
#pragma unroll
      for (int q = 0; q < 4; q++) scq[q] = __shfl(sc, 4 * g + q);
#pragma unroll
      for (int dt = 0; dt < 4; dt++)
#pragma unroll
        for (int q = 0; q < 4; q++) Racc[dt][q] *= scq[q];
    }
    float p[16], ls = 0.f;
#pragma unroll
    for (int lt = 0; lt < 4; lt++)
#pragma unroll
      for (int q = 0; q < 4; q++) {
        const float e = exp2_fast(cst[lt][q] - mrun);
        p[lt * 4 + q] = e;
        ls += e;
      }
    ls += __shfl_xor(ls, 16);
    ls += __shfl_xor(ls, 32);
    lrun += ls;

    unsigned int pk[8];
#pragma unroll
    for (int lt = 0; lt < 4; lt++) {
      pk[lt * 2 + 0] = cvtpk(p[lt * 4 + 0], p[lt * 4 + 1]);
      pk[lt * 2 + 1] = cvtpk(p[lt * 4 + 2], p[lt * 4 + 3]);
    }

    // ---- phase 2: R += P @ Mt ----
#pragma unroll
    for (int kk = 0; kk < 2; kk++) {
      unsigned int aw[4];
#pragma unroll
      for (int wd = 0; wd < 4; wd++) {
        const int srcl = lo + 16 * (2 * (g & 1) + (wd >> 1));
        const unsigned int a0 = __shfl(pk[(2 * kk) * 2 + (wd & 1)], srcl);
        const unsigned int a1 = __shfl(pk[(2 * kk + 1) * 2 + (wd & 1)], srcl);
        aw[wd] = (g & 2) ? a1 : a0;
      }
      const u32x4 awv = {aw[0], aw[1], aw[2], aw[3]};
      const bf16x8 afr = __builtin_bit_cast(bf16x8, awv);
#pragma unroll
      for (int dt = 0; dt < 4; dt++) {
        const bf16x8 bfr =
            *(const bf16x8*)&sMt[cur][(16 * dt + lo) * 64 + ((32 * kk + 8 * g) ^ ((lo & 7) * 8))];
        Racc[dt] = __builtin_amdgcn_mfma_f32_16x16x32_bf16(afr, bfr, Racc[dt], 0, 0, 0);
      }
    }

    // write prefetched tile into the other buffer (prev iter's barrier made it free)
    if (it < 31) {
      const int nxt = cur ^ 1;
      *(u16x8*)&sMn[nxt][d0] = rn0; *(u16x8*)&sMn[nxt][d1] = rn1;
      *(u16x8*)&sMt[nxt][d0] = rt0; *(u16x8*)&sMt[nxt][d1] = rt1;
    }
    __syncthreads();
  }

  if (g == 0) {
    const int row = row0 + 16 * w + lo;
    m_part[(size_t)row * NSPLIT + sp] = mrun;
    l_part[(size_t)row * NSPLIT + sp] = lrun;
  }
#pragma unroll
  for (int dt = 0; dt < 4; dt++)
#pragma unroll
    for (int q = 0; q < 4; q++) {
      const int row = row0 + 16 * w + 4 * g + q;
      r_part[((size_t)row * NSPLIT + sp) * 64 + 16 * dt + lo] = Racc[dt][q];
    }
}

// ---------------- Kernel F: combine + output dot (blocks<512) / w_read (blocks>=512) ----------------
__global__ __launch_bounds__(256) void k_post(const float* __restrict__ m_part,
                                              const float* __restrict__ l_part,
                                              const float* __restrict__ r_part,
                                              const float* __restrict__ h,
                                              const float* __restrict__ M,
                                              const float* __restrict__ invn,
                                              const unsigned short* __restrict__ kn_bf,
                                              const float* __restrict__ Wout,
                                              const float* __restrict__ bout,
                                              float* __restrict__ out) {
  const int lane = threadIdx.x & 63, w = threadIdx.x >> 6;
  const int bx = blockIdx.x;
  if (bx < 512) {
    const int row = bx * 4 + w;
    const float mp = (lane < NSPLIT) ? m_part[(size_t)row * NSPLIT + lane] : -3.0e38f;
    float m = mp;
#pragma unroll
    for (int off = 32; off >= 1; off >>= 1) m = fmaxf(m, __shfl_xor(m, off));
    float l = (lane < NSPLIT) ? l_part[(size_t)row * NSPLIT + lane] * exp2_fast(mp - m) : 0.f;
#pragma unroll
    for (int off = 32; off >= 1; off >>= 1) l += __shfl_xor(l, off);
    float rd = 0.f;
    for (int sp2 = 0; sp2 < NSPLIT; sp2++) {
      const float msp = m_part[(size_t)row * NSPLIT + sp2];
      rd += r_part[((size_t)row * NSPLIT + sp2) * 64 + lane] * exp2_fast(msp - m);
    }
    rd /= l;
    float acc = Wout[CTRL + lane] * rd;
    for (int k = lane; k < CTRL; k += 64) acc += h[(size_t)row * CTRL + k] * Wout[k];
#pragma unroll
    for (int off = 32; off >= 1; off >>= 1) acc += __shfl_xor(acc, off);
    if (lane == 0) out[row] = acc + bout[0];
  } else {
    const int loc = (bx - 512) * 4 + w;
    const float mp = (lane < NSPLIT) ? m_part[(size_t)(B_SZ - 1) * NSPLIT + lane] : -3.0e38f;
    float m = mp;
#pragma unroll
    for (int off = 32; off >= 1; off >>= 1) m = fmaxf(m, __shfl_xor(m, off));
    float l = (lane < NSPLIT) ? l_part[(size_t)(B_SZ - 1) * NSPLIT + lane] * exp2_fast(mp - m) : 0.f;
#pragma unroll
    for (int off = 32; off >= 1; off >>= 1) l += __shfl_xor(l, off);
    float v = bf2f(kn_bf[(size_t)(B_SZ - 1) * 64 + lane]) * M[(size_t)loc * 64 + lane];
#pragma unroll
    for (int off = 32; off >= 1; off >>= 1) v += __shfl_xor(v, off);
    const float sim = v * invn[loc] * LOG2E;
    if (lane == 0) out[2048 + 512 + 1 + loc] = exp2_fast(sim - m) / l;
  }
}

extern "C" void kernel_launch(void* const* d_in, const int* in_sizes, int n_in,
                              void* d_out, int out_size, void* d_ws, size_t ws_size,
                              hipStream_t stream) {
  const float* x = (const float*)d_in[0];
  const float* Wh = (const float*)d_in[1];
  const float* bh = (const float*)d_in[2];
  const float* Wg = (const float*)d_in[3];
  const float* bg = (const float*)d_in[4];
  const float* Wk = (const float*)d_in[5];
  const float* bk = (const float*)d_in[6];
  const float* M = (const float*)d_in[7];
  const float* Wout = (const float*)d_in[8];
  const float* bout = (const float*)d_in[9];
  float* out = (float*)d_out;

  float* ws = (float*)d_ws;
  float* h = ws;                            // 1,048,576 f
  float* invn = h + 1048576;                // 65,536 f
  float* m_part = invn + 65536;             // 65,536 f
  float* l_part = m_part + 65536;           // 65,536 f
  float* r_part = l_part + 65536;           // 4,194,304 f
  unsigned short* kn_bf = (unsigned short*)(r_part + 4194304);      // 131,072 us
  unsigned short* Mn_t = kn_bf + 131072;                            // 4,194,304 us
  unsigned short* Mt_t = Mn_t + 4194304;                            // 4,194,304 us

  hipLaunchKernelGGL(k_hgemm, dim3(B_SZ / 64, CTRL / 64), dim3(256), 0, stream, x, Wh, bh, h);
  hipLaunchKernelGGL(k_readkey, dim3(513), dim3(256), 0, stream, h, Wk, bk, x, Wg, bg, kn_bf, out);
  hipLaunchKernelGGL(k_prep, dim3(N_LOC / 64), dim3(256), 0, stream, M, invn, Mn_t, Mt_t);
  hipLaunchKernelGGL(k_attn, dim3(B_SZ / 64, NSPLIT), dim3(256), 0, stream,
                     kn_bf, Mn_t, Mt_t, m_part, l_part, r_part);
  hipLaunchKernelGGL(k_post, dim3(512 + N_LOC / 4), dim3(256), 0, stream,
                     m_part, l_part, r_part, h, M, invn, kn_bf, Wout, bout, out);
}

// Round 4
// 123.475 us; speedup vs baseline: 8.9144x; 1.3264x over previous
//
#include <hip/hip_runtime.h>

#define B_SZ 2048
#define IN_DIM 512
#define CTRL 512
#define N_LOC 65536
#define NSPLIT 32
#define EPSV 1e-8f
#define LOG2E 1.4426950408889634f

typedef __attribute__((ext_vector_type(8))) short bf16x8;
typedef __attribute__((ext_vector_type(4))) float f32x4;
typedef __attribute__((ext_vector_type(16))) float f32x16;
typedef __attribute__((ext_vector_type(8))) unsigned short u16x8;

static __device__ __forceinline__ unsigned int cvtpk(float lo, float hi) {
  unsigned int r;
  asm("v_cvt_pk_bf16_f32 %0, %1, %2" : "=v"(r) : "v"(lo), "v"(hi));
  return r;
}
static __device__ __forceinline__ unsigned short f2bf_hw(float f) {
  return (unsigned short)(cvtpk(f, f) & 0xffffu);
}
static __device__ __forceinline__ float exp2_fast(float x) {
  float r;
  asm("v_exp_f32 %0, %1" : "=v"(r) : "v"(x));
  return r;
}

// ---------------- Kernel P2: xb = bf16(x); Wht = bf16(Wh^T) [col][k] ----------------
__global__ __launch_bounds__(256) void k_prep2(const float* __restrict__ x,
                                               const float* __restrict__ Wh,
                                               unsigned short* __restrict__ xb,
                                               unsigned short* __restrict__ Wht) {
  const int bx = blockIdx.x, t = threadIdx.x;
  if (bx < 512) {
    const int base = bx * 2048 + t * 8;
    const float4 a = *(const float4*)&x[base];
    const float4 b = *(const float4*)&x[base + 4];
    u16x8 o;
    unsigned int u0 = cvtpk(a.x, a.y), u1 = cvtpk(a.z, a.w);
    unsigned int u2 = cvtpk(b.x, b.y), u3 = cvtpk(b.z, b.w);
    o[0] = (unsigned short)u0; o[1] = (unsigned short)(u0 >> 16);
    o[2] = (unsigned short)u1; o[3] = (unsigned short)(u1 >> 16);
    o[4] = (unsigned short)u2; o[5] = (unsigned short)(u2 >> 16);
    o[6] = (unsigned short)u3; o[7] = (unsigned short)(u3 >> 16);
    *(u16x8*)&xb[base] = o;
  } else {
    __shared__ float ld[64][65];
    const int id = bx - 512;
    const int ti = id >> 3, tj = id & 7;  // k-block, col-block
#pragma unroll
    for (int i = 0; i < 4; i++) {
      const int c = t + i * 256;
      const int r = c >> 4, c4 = (c & 15) * 4;
      const float4 v = *(const float4*)&Wh[(size_t)(ti * 64 + r) * CTRL + tj * 64 + c4];
      ld[r][c4] = v.x; ld[r][c4 + 1] = v.y; ld[r][c4 + 2] = v.z; ld[r][c4 + 3] = v.w;
    }
    __syncthreads();
#pragma unroll
    for (int i = 0; i < 2; i++) {
      const int c = t + i * 256;
      const int col = c >> 3, k8 = (c & 7) * 8;
      u16x8 o;
#pragma unroll
      for (int j = 0; j < 4; j++) {
        unsigned int u = cvtpk(ld[k8 + 2 * j][col], ld[k8 + 2 * j + 1][col]);
        o[2 * j] = (unsigned short)u;
        o[2 * j + 1] = (unsigned short)(u >> 16);
      }
      *(u16x8*)&Wht[(size_t)(tj * 64 + col) * IN_DIM + ti * 64 + k8] = o;
    }
  }
}

// ---------------- Kernel A: h = tanh(x @ W_h + b_h), bf16 MFMA ----------------
// grid (32, 4): 64 rows x 128 cols per block, 256 thr = 4 waves.
__global__ __launch_bounds__(256) void k_hgemm(const unsigned short* __restrict__ xb,
                                               const unsigned short* __restrict__ Wht,
                                               const float* __restrict__ bh,
                                               float* __restrict__ h) {
  __shared__ __align__(16) unsigned short xs[64 * 32];
  __shared__ __align__(16) unsigned short wsb[128 * 32];
  const int t = threadIdx.x, lane = t & 63, w = t >> 6, lo = lane & 15, g = lane >> 4;
  const int bm = blockIdx.x * 64, bn = blockIdx.y * 128;
  f32x4 acc[4][2];
#pragma unroll
  for (int rt = 0; rt < 4; rt++)
#pragma unroll
    for (int c = 0; c < 2; c++) acc[rt][c] = (f32x4){0.f, 0.f, 0.f, 0.f};

  for (int k0 = 0; k0 < IN_DIM; k0 += 32) {
    {
      const int r = t >> 2, k8 = (t & 3) * 8;
      *(u16x8*)&xs[r * 32 + (k8 ^ ((r & 3) * 8))] =
          *(const u16x8*)&xb[(size_t)(bm + r) * IN_DIM + k0 + k8];
#pragma unroll
      for (int i = 0; i < 2; i++) {
        const int c = t + i * 256;
        const int col = c >> 2, kk8 = (c & 3) * 8;
        *(u16x8*)&wsb[col * 32 + (kk8 ^ ((col & 3) * 8))] =
            *(const u16x8*)&Wht[(size_t)(bn + col) * IN_DIM + k0 + kk8];
      }
    }
    __syncthreads();
    const int koff = (8 * g) ^ ((lo & 3) * 8);
#pragma unroll
    for (int rt = 0; rt < 4; rt++) {
      const bf16x8 afr = *(const bf16x8*)&xs[(16 * rt + lo) * 32 + koff];
#pragma unroll
      for (int c = 0; c < 2; c++) {
        const bf16x8 bfr = *(const bf16x8*)&wsb[(32 * w + 16 * c + lo) * 32 + koff];
        acc[rt][c] = __builtin_amdgcn_mfma_f32_16x16x32_bf16(afr, bfr, acc[rt][c], 0, 0, 0);
      }
    }
    __syncthreads();
  }
#pragma unroll
  for (int rt = 0; rt < 4; rt++)
#pragma unroll
    for (int c = 0; c < 2; c++) {
      const int col = bn + 32 * w + 16 * c + lo;
#pragma unroll
      for (int q = 0; q < 4; q++) {
        const int row = bm + 16 * rt + 4 * g + q;
        h[(size_t)row * CTRL + col] = tanhf(acc[rt][c][q] + bh[col]);
      }
    }
}

// ---------------- Kernel C: read-key (+ tail block) ----------------
__global__ __launch_bounds__(256) void k_readkey(const float* __restrict__ h,
                                                 const float* __restrict__ Wk,
                                                 const float* __restrict__ bk,
                                                 const float* __restrict__ x,
                                                 const float* __restrict__ Wg,
                                                 const float* __restrict__ bg,
                                                 unsigned short* __restrict__ kn_bf,
                                                 float* __restrict__ out) {
  __shared__ float red[4];
  if (blockIdx.x < 512) {
    const int lane = threadIdx.x & 63;
    const int row = blockIdx.x * 4 + (threadIdx.x >> 6);
    const float* hr = &h[(size_t)row * CTRL];
    float acc = 0.f;
    for (int k = 0; k < CTRL; k += 4) {
      const float4 hv = *(const float4*)&hr[k];
      acc += hv.x * Wk[(k + 0) * 64 + lane];
      acc += hv.y * Wk[(k + 1) * 64 + lane];
      acc += hv.z * Wk[(k + 2) * 64 + lane];
      acc += hv.w * Wk[(k + 3) * 64 + lane];
    }
    const float v = tanhf(acc + bk[lane]);
    float ss = v * v;
#pragma unroll
    for (int off = 32; off >= 1; off >>= 1) ss += __shfl_xor(ss, off);
    kn_bf[(size_t)row * 64 + lane] = f2bf_hw(v / (sqrtf(ss) + EPSV));
  } else {
    const int t = threadIdx.x;
    out[2048 + t] = h[(size_t)(B_SZ - 1) * CTRL + t];
    out[2048 + 256 + t] = h[(size_t)(B_SZ - 1) * CTRL + 256 + t];
    float p = x[(size_t)(B_SZ - 1) * IN_DIM + t] * Wg[t] +
              x[(size_t)(B_SZ - 1) * IN_DIM + 256 + t] * Wg[256 + t];
#pragma unroll
    for (int off = 32; off >= 1; off >>= 1) p += __shfl_xor(p, off);
    if ((t & 63) == 0) red[t >> 6] = p;
    __syncthreads();
    if (t == 0) out[2048 + 512] = red[0] + red[1] + red[2] + red[3] + bg[0];
  }
}

// ---------------- Kernel D: bf16 tiled copies of M ----------------
// Mn_t: [1024][64 loc][64 d], normalized * LOG2E. Mt_t: [1024][64 d][64 loc], raw.
__global__ __launch_bounds__(256) void k_prep(const float* __restrict__ M,
                                              unsigned short* __restrict__ Mn_t,
                                              unsigned short* __restrict__ Mt_t) {
  const int b = blockIdx.x, t = threadIdx.x;
  const int c4 = t & 15, lg = t >> 4;
  float vv[4][4], ss[4];
#pragma unroll
  for (int r = 0; r < 4; r++) {
    const int loc = b * 64 + lg * 4 + r;
    const float4 f = *(const float4*)&M[(size_t)loc * 64 + c4 * 4];
    vv[r][0] = f.x; vv[r][1] = f.y; vv[r][2] = f.z; vv[r][3] = f.w;
    ss[r] = f.x * f.x + f.y * f.y + f.z * f.z + f.w * f.w;
  }
#pragma unroll
  for (int r = 0; r < 4; r++)
#pragma unroll
    for (int off = 1; off < 16; off <<= 1) ss[r] += __shfl_xor(ss[r], off);
#pragma unroll
  for (int r = 0; r < 4; r++) {
    const float s = (1.f / (sqrtf(ss[r]) + EPSV)) * LOG2E;
    uint2 u;
    u.x = cvtpk(vv[r][0] * s, vv[r][1] * s);
    u.y = cvtpk(vv[r][2] * s, vv[r][3] * s);
    *(uint2*)&Mn_t[(size_t)b * 4096 + (lg * 4 + r) * 64 + c4 * 4] = u;
  }
#pragma unroll
  for (int j = 0; j < 4; j++) {
    uint2 u;
    u.x = cvtpk(vv[0][j], vv[1][j]);
    u.y = cvtpk(vv[2][j], vv[3][j]);
    *(uint2*)&Mt_t[(size_t)b * 4096 + (c4 * 4 + j) * 64 + lg * 4] = u;
  }
}

// ---------------- Kernel E: fused attention partials (32x32 MFMA, no-max softmax) ----
// grid (8, NSPLIT), 512 thr = 8 waves; wave w owns batch rows row0+32w..+31.
__global__ __launch_bounds__(512) void k_attn(const unsigned short* __restrict__ kn_bf,
                                              const unsigned short* __restrict__ Mn_t,
                                              const unsigned short* __restrict__ Mt_t,
                                              float* __restrict__ l_part,
                                              float* __restrict__ r_part,
                                              float* __restrict__ wdump) {
  __shared__ __align__(16) unsigned short sKn[16384];     // 256 rows x 64
  __shared__ __align__(16) unsigned short sMn[2][4096];
  __shared__ __align__(16) unsigned short sMt[2][4096];
  __shared__ __align__(16) unsigned short sP[8][2048];    // per wave: 32 rows x 64 locs
  const int rb = blockIdx.x, sp = blockIdx.y;
  const int t = threadIdx.x, lane = t & 63, w = t >> 6;
  const int l31 = lane & 31, h = lane >> 5, l7 = lane & 7;
  const int row0 = rb * 256;

  // stage kn: 256 rows x 64 bf16 (2048 chunks / 512 thr = 4)
#pragma unroll
  for (int i = 0; i < 4; i++) {
    const int c = t + i * 512;
    const int r = c >> 3, col8 = (c & 7) * 8;
    *(u16x8*)&sKn[r * 64 + (col8 ^ ((r & 7) * 8))] =
        *(const u16x8*)&kn_bf[(size_t)(row0 + r) * 64 + col8];
  }
  // stage first M tile (1 chunk per thread per array)
  const int sr = t >> 3, sc8 = (t & 7) * 8;
  const int sdst = sr * 64 + (sc8 ^ ((sr & 7) * 8));
  {
    const size_t gb = (size_t)(sp * 32) * 4096 + t * 8;
    *(u16x8*)&sMn[0][sdst] = *(const u16x8*)&Mn_t[gb];
    *(u16x8*)&sMt[0][sdst] = *(const u16x8*)&Mt_t[gb];
  }
  __syncthreads();

  f32x16 Racc[2];
#pragma unroll
  for (int dt = 0; dt < 2; dt++) Racc[dt] = (f32x16)(0.f);
  float lrun = 0.f;

  u16x8 rn, rt;
  for (int it = 0; it < 32; ++it) {
    const int cur = it & 1;
    if (it < 31) {
      const size_t gn = (size_t)(sp * 32 + it + 1) * 4096 + t * 8;
      rn = *(const u16x8*)&Mn_t[gn];
      rt = *(const u16x8*)&Mt_t[gn];
    }

    // ---- phase 1: S^T[loc][brow] = Mn . kn^T ----
    f32x16 cst[2];
#pragma unroll
    for (int lt = 0; lt < 2; lt++) cst[lt] = (f32x16)(0.f);
#pragma unroll
    for (int kk = 0; kk < 4; kk++) {
      const int koff = (16 * kk + 8 * h) ^ (l7 * 8);
      const bf16x8 bfr = *(const bf16x8*)&sKn[(32 * w + l31) * 64 + koff];
#pragma unroll
      for (int lt = 0; lt < 2; lt++) {
        const bf16x8 afr = *(const bf16x8*)&sMn[cur][(32 * lt + l31) * 64 + koff];
        cst[lt] = __builtin_amdgcn_mfma_f32_32x32x16_bf16(afr, bfr, cst[lt], 0, 0, 0);
      }
    }

    // ---- softmax: p = exp2(s), no max tracking (|s| <= ~1.5) ----
#pragma unroll
    for (int lt = 0; lt < 2; lt++)
#pragma unroll
      for (int r = 0; r < 16; r++) {
        const float e = exp2_fast(cst[lt][r]);
        cst[lt][r] = e;
        lrun += e;
      }

    // dump raw P for batch row 2047 (rb==7, wave 7, l31==31)
    if (rb == 7 && w == 7 && l31 == 31) {
#pragma unroll
      for (int lt = 0; lt < 2; lt++)
#pragma unroll
        for (int rr = 0; rr < 4; rr++) {
          float4 o = make_float4(cst[lt][4 * rr], cst[lt][4 * rr + 1],
                                 cst[lt][4 * rr + 2], cst[lt][4 * rr + 3]);
          *(float4*)&wdump[sp * 2048 + it * 64 + 32 * lt + 8 * rr + 4 * h] = o;
        }
    }

    // ---- pack P -> per-wave LDS [32 rows][64 locs] swizzled ----
#pragma unroll
    for (int lt = 0; lt < 2; lt++)
#pragma unroll
      for (int rr = 0; rr < 4; rr++) {
        uint2 u;
        u.x = cvtpk(cst[lt][4 * rr + 0], cst[lt][4 * rr + 1]);
        u.y = cvtpk(cst[lt][4 * rr + 2], cst[lt][4 * rr + 3]);
        *(uint2*)&sP[w][l31 * 64 + ((32 * lt + 8 * rr + 4 * h) ^ (l7 * 8))] = u;
      }
    asm volatile("s_waitcnt lgkmcnt(0)" ::: "memory");
    __builtin_amdgcn_sched_barrier(0);

    // ---- phase 2: R[brow][d] += P @ Mt ----
#pragma unroll
    for (int kk = 0; kk < 4; kk++) {
      const int koff = (16 * kk + 8 * h) ^ (l7 * 8);
      const bf16x8 afr = *(const bf16x8*)&sP[w][l31 * 64 + koff];
#pragma unroll
      for (int dt = 0; dt < 2; dt++) {
        const bf16x8 bfr = *(const bf16x8*)&sMt[cur][(32 * dt + l31) * 64 + koff];
        Racc[dt] = __builtin_amdgcn_mfma_f32_32x32x16_bf16(afr, bfr, Racc[dt], 0, 0, 0);
      }
    }

    if (it < 31) {
      const int nxt = cur ^ 1;
      *(u16x8*)&sMn[nxt][sdst] = rn;
      *(u16x8*)&sMt[nxt][sdst] = rt;
    }
    __syncthreads();
  }

  // final l reduce: lane l and l^32 hold complementary halves of brow l31
  lrun += __shfl_xor(lrun, 32);
  if (h == 0) l_part[(size_t)(row0 + 32 * w + l31) * NSPLIT + sp] = lrun;

#pragma unroll
  for (int dt = 0; dt < 2; dt++)
#pragma unroll
    for (int r = 0; r < 16; r++) {
      const int brow = (r & 3) + 8 * (r >> 2) + 4 * h;
      const int row = row0 + 32 * w + brow;
      r_part[((size_t)row * NSPLIT + sp) * 64 + 32 * dt + l31] = Racc[dt][r];
    }
}

// ---------------- Kernel F: combine + output dot / w_read divide ----------------
__global__ __launch_bounds__(256) void k_post(const float* __restrict__ l_part,
                                              const float* __restrict__ r_part,
                                              const float* __restrict__ h,
                                              const float* __restrict__ Wout,
                                              const float* __restrict__ bout,
                                              const float* __restrict__ wdump,
                                              float* __restrict__ out) {
  const int lane = threadIdx.x & 63, w = threadIdx.x >> 6;
  const int bx = blockIdx.x;
  if (bx < 512) {
    const int row = bx * 4 + w;
    float l = (lane < NSPLIT) ? l_part[(size_t)row * NSPLIT + lane] : 0.f;
#pragma unroll
    for (int off = 32; off >= 1; off >>= 1) l += __shfl_xor(l, off);
    float rd = 0.f;
    for (int sp2 = 0; sp2 < NSPLIT; sp2++)
      rd += r_part[((size_t)row * NSPLIT + sp2) * 64 + lane];
    rd /= l;
    float acc = Wout[CTRL + lane] * rd;
    for (int k = lane; k < CTRL; k += 64) acc += h[(size_t)row * CTRL + k] * Wout[k];
#pragma unroll
    for (int off = 32; off >= 1; off >>= 1) acc += __shfl_xor(acc, off);
    if (lane == 0) out[row] = acc + bout[0];
  } else {
    float l = (lane < NSPLIT) ? l_part[(size_t)(B_SZ - 1) * NSPLIT + lane] : 0.f;
#pragma unroll
    for (int off = 32; off >= 1; off >>= 1) l += __shfl_xor(l, off);
    const float rl = 1.f / l;
    const int i = ((bx - 512) * 256 + threadIdx.x) * 4;
    const float4 v = *(const float4*)&wdump[i];
    float4 o = make_float4(v.x * rl, v.y * rl, v.z * rl, v.w * rl);
    *(float4*)&out[2048 + 512 + 1 + i] = o;
  }
}

extern "C" void kernel_launch(void* const* d_in, const int* in_sizes, int n_in,
                              void* d_out, int out_size, void* d_ws, size_t ws_size,
                              hipStream_t stream) {
  const float* x = (const float*)d_in[0];
  const float* Wh = (const float*)d_in[1];
  const float* bh = (const float*)d_in[2];
  const float* Wg = (const float*)d_in[3];
  const float* bg = (const float*)d_in[4];
  const float* Wk = (const float*)d_in[5];
  const float* bk = (const float*)d_in[6];
  const float* M = (const float*)d_in[7];
  const float* Wout = (const float*)d_in[8];
  const float* bout = (const float*)d_in[9];
  float* out = (float*)d_out;

  float* ws = (float*)d_ws;
  float* h = ws;                                  // 1,048,576 f
  float* r_part = h + 1048576;                    // 4,194,304 f
  float* l_part = r_part + 4194304;               // 65,536 f
  float* wdump = l_part + 65536;                  // 65,536 f
  unsigned short* kn_bf = (unsigned short*)(wdump + 65536);   // 131,072 us
  unsigned short* Mn_t = kn_bf + 131072;          // 4,194,304 us
  unsigned short* Mt_t = Mn_t + 4194304;          // 4,194,304 us
  unsigned short* xb = Mt_t + 4194304;            // 1,048,576 us
  unsigned short* Wht = xb + 1048576;             // 262,144 us   (total ~40 MB)

  hipLaunchKernelGGL(k_prep2, dim3(576), dim3(256), 0, stream, x, Wh, xb, Wht);
  hipLaunchKernelGGL(k_hgemm, dim3(32, 4), dim3(256), 0, stream, xb, Wht, bh, h);
  hipLaunchKernelGGL(k_readkey, dim3(513), dim3(256), 0, stream, h, Wk, bk, x, Wg, bg, kn_bf, out);
  hipLaunchKernelGGL(k_prep, dim3(N_LOC / 64), dim3(256), 0, stream, M, Mn_t, Mt_t);
  hipLaunchKernelGGL(k_attn, dim3(8, NSPLIT), dim3(512), 0, stream,
                     kn_bf, Mn_t, Mt_t, l_part, r_part, wdump);
  hipLaunchKernelGGL(k_post, dim3(512 + 64), dim3(256), 0, stream,
                     l_part, r_part, h, Wout, bout, wdump, out);
}

// Round 5
// 109.459 us; speedup vs baseline: 10.0559x; 1.1280x over previous
//
#include <hip/hip_runtime.h>

#define B_SZ 2048
#define IN_DIM 512
#define CTRL 512
#define N_LOC 65536
#define NSPLIT 64
#define LPS (N_LOC / NSPLIT)   // 1024 locs per split, 16 tiles of 64
#define EPSV 1e-8f
#define LOG2E 1.4426950408889634f

typedef __attribute__((ext_vector_type(8))) short bf16x8;
typedef __attribute__((ext_vector_type(4))) float f32x4;
typedef __attribute__((ext_vector_type(16))) float f32x16;
typedef __attribute__((ext_vector_type(4))) unsigned int u32x4;
typedef __attribute__((ext_vector_type(8))) unsigned short u16x8;

static __device__ __forceinline__ unsigned int cvtpk(float lo, float hi) {
  unsigned int r;
  asm("v_cvt_pk_bf16_f32 %0, %1, %2" : "=v"(r) : "v"(lo), "v"(hi));
  return r;
}
static __device__ __forceinline__ unsigned short f2bf_hw(float f) {
  return (unsigned short)(cvtpk(f, f) & 0xffffu);
}
static __device__ __forceinline__ float bf2f(unsigned short u) {
  return __builtin_bit_cast(float, ((unsigned int)u) << 16);
}
static __device__ __forceinline__ float exp2_fast(float x) {
  float r;
  asm("v_exp_f32 %0, %1" : "=v"(r) : "v"(x));
  return r;
}

// ---------------- Kernel P: all preprocessing ----------------
// bx<512: xb=bf16(x). 512..575: Wht=bf16(Wh^T)[col][k]. 576..583: Wkt=bf16(Wk^T)[col][k].
// 584..1607: M tiles -> Mn_t [tile][loc][d] (*invn*LOG2E), Mt_t [tile][d][loc].
__global__ __launch_bounds__(256) void k_prep_all(const float* __restrict__ x,
                                                  const float* __restrict__ Wh,
                                                  const float* __restrict__ Wk,
                                                  const float* __restrict__ M,
                                                  unsigned short* __restrict__ xb,
                                                  unsigned short* __restrict__ Wht,
                                                  unsigned short* __restrict__ Wkt,
                                                  unsigned short* __restrict__ Mn_t,
                                                  unsigned short* __restrict__ Mt_t) {
  const int bx = blockIdx.x, t = threadIdx.x;
  if (bx < 512) {
    const int base = bx * 2048 + t * 8;
    const float4 a = *(const float4*)&x[base];
    const float4 b = *(const float4*)&x[base + 4];
    u16x8 o;
    unsigned int u0 = cvtpk(a.x, a.y), u1 = cvtpk(a.z, a.w);
    unsigned int u2 = cvtpk(b.x, b.y), u3 = cvtpk(b.z, b.w);
    o[0] = (unsigned short)u0; o[1] = (unsigned short)(u0 >> 16);
    o[2] = (unsigned short)u1; o[3] = (unsigned short)(u1 >> 16);
    o[4] = (unsigned short)u2; o[5] = (unsigned short)(u2 >> 16);
    o[6] = (unsigned short)u3; o[7] = (unsigned short)(u3 >> 16);
    *(u16x8*)&xb[base] = o;
  } else if (bx < 584) {
    __shared__ float ld[64][65];
    const bool isWh = bx < 576;
    const int id = isWh ? bx - 512 : bx - 576;
    const int ti = isWh ? (id >> 3) : id;      // k-block
    const int tj = isWh ? (id & 7) : 0;        // col-block
    const int ncol = isWh ? CTRL : 64;
    const float* src = isWh ? Wh : Wk;
#pragma unroll
    for (int i = 0; i < 4; i++) {
      const int c = t + i * 256;
      const int r = c >> 4, c4 = (c & 15) * 4;
      const float4 v = *(const float4*)&src[(size_t)(ti * 64 + r) * ncol + tj * 64 + c4];
      ld[r][c4] = v.x; ld[r][c4 + 1] = v.y; ld[r][c4 + 2] = v.z; ld[r][c4 + 3] = v.w;
    }
    __syncthreads();
    unsigned short* dst = isWh ? Wht : Wkt;
#pragma unroll
    for (int i = 0; i < 2; i++) {
      const int c = t + i * 256;
      const int col = c >> 3, k8 = (c & 7) * 8;
      u16x8 o;
#pragma unroll
      for (int j = 0; j < 4; j++) {
        unsigned int u = cvtpk(ld[k8 + 2 * j][col], ld[k8 + 2 * j + 1][col]);
        o[2 * j] = (unsigned short)u;
        o[2 * j + 1] = (unsigned short)(u >> 16);
      }
      *(u16x8*)&dst[(size_t)(tj * 64 + col) * IN_DIM + ti * 64 + k8] = o;
    }
  } else {
    const int b = bx - 584;
    const int c4 = t & 15, lg = t >> 4;
    float vv[4][4], ss[4];
#pragma unroll
    for (int r = 0; r < 4; r++) {
      const int loc = b * 64 + lg * 4 + r;
      const float4 f = *(const float4*)&M[(size_t)loc * 64 + c4 * 4];
      vv[r][0] = f.x; vv[r][1] = f.y; vv[r][2] = f.z; vv[r][3] = f.w;
      ss[r] = f.x * f.x + f.y * f.y + f.z * f.z + f.w * f.w;
    }
#pragma unroll
    for (int r = 0; r < 4; r++)
#pragma unroll
      for (int off = 1; off < 16; off <<= 1) ss[r] += __shfl_xor(ss[r], off);
#pragma unroll
    for (int r = 0; r < 4; r++) {
      const float s = (1.f / (sqrtf(ss[r]) + EPSV)) * LOG2E;
      uint2 u;
      u.x = cvtpk(vv[r][0] * s, vv[r][1] * s);
      u.y = cvtpk(vv[r][2] * s, vv[r][3] * s);
      *(uint2*)&Mn_t[(size_t)b * 4096 + (lg * 4 + r) * 64 + c4 * 4] = u;
    }
#pragma unroll
    for (int j = 0; j < 4; j++) {
      uint2 u;
      u.x = cvtpk(vv[0][j], vv[1][j]);
      u.y = cvtpk(vv[2][j], vv[3][j]);
      *(uint2*)&Mt_t[(size_t)b * 4096 + (c4 * 4 + j) * 64 + lg * 4] = u;
    }
  }
}

// ---------------- Kernel A: h = tanh(x @ W_h + b_h), bf16 MFMA ----------------
__global__ __launch_bounds__(256) void k_hgemm(const unsigned short* __restrict__ xb,
                                               const unsigned short* __restrict__ Wht,
                                               const float* __restrict__ bh,
                                               float* __restrict__ h) {
  __shared__ __align__(16) unsigned short xs[64 * 32];
  __shared__ __align__(16) unsigned short wsb[128 * 32];
  const int t = threadIdx.x, lane = t & 63, w = t >> 6, lo = lane & 15, g = lane >> 4;
  const int bm = blockIdx.x * 64, bn = blockIdx.y * 128;
  f32x4 acc[4][2];
#pragma unroll
  for (int rt = 0; rt < 4; rt++)
#pragma unroll
    for (int c = 0; c < 2; c++) acc[rt][c] = (f32x4){0.f, 0.f, 0.f, 0.f};

  for (int k0 = 0; k0 < IN_DIM; k0 += 32) {
    {
      const int r = t >> 2, k8 = (t & 3) * 8;
      *(u16x8*)&xs[r * 32 + (k8 ^ ((r & 3) * 8))] =
          *(const u16x8*)&xb[(size_t)(bm + r) * IN_DIM + k0 + k8];
#pragma unroll
      for (int i = 0; i < 2; i++) {
        const int c = t + i * 256;
        const int col = c >> 2, kk8 = (c & 3) * 8;
        *(u16x8*)&wsb[col * 32 + (kk8 ^ ((col & 3) * 8))] =
            *(const u16x8*)&Wht[(size_t)(bn + col) * IN_DIM + k0 + kk8];
      }
    }
    __syncthreads();
    const int koff = (8 * g) ^ ((lo & 3) * 8);
#pragma unroll
    for (int rt = 0; rt < 4; rt++) {
      const bf16x8 afr = *(const bf16x8*)&xs[(16 * rt + lo) * 32 + koff];
#pragma unroll
      for (int c = 0; c < 2; c++) {
        const bf16x8 bfr = *(const bf16x8*)&wsb[(32 * w + 16 * c + lo) * 32 + koff];
        acc[rt][c] = __builtin_amdgcn_mfma_f32_16x16x32_bf16(afr, bfr, acc[rt][c], 0, 0, 0);
      }
    }
    __syncthreads();
  }
#pragma unroll
  for (int rt = 0; rt < 4; rt++)
#pragma unroll
    for (int c = 0; c < 2; c++) {
      const int col = bn + 32 * w + 16 * c + lo;
#pragma unroll
      for (int q = 0; q < 4; q++) {
        const int row = bm + 16 * rt + 4 * g + q;
        h[(size_t)row * CTRL + col] = tanhf(acc[rt][c][q] + bh[col]);
      }
    }
}

// ---------------- Kernel C: read-key via MFMA (+ tail block 16) ----------------
// blocks 0..15: 128 rows each, 4 waves x 32 rows; key = normalize(tanh(h@Wk+bk)).
__global__ __launch_bounds__(256) void k_readkey(const float* __restrict__ h_,
                                                 const unsigned short* __restrict__ Wkt,
                                                 const float* __restrict__ bk,
                                                 const float* __restrict__ x,
                                                 const float* __restrict__ Wg,
                                                 const float* __restrict__ bg,
                                                 unsigned short* __restrict__ kn_bf,
                                                 float* __restrict__ out) {
  const int t = threadIdx.x, lane = t & 63, w = t >> 6;
  const int l31 = lane & 31, hh = lane >> 5;
  if (blockIdx.x < 16) {
    const int row0 = blockIdx.x * 128 + 32 * w;
    f32x16 acc[2];
    acc[0] = (f32x16)(0.f); acc[1] = (f32x16)(0.f);
    for (int kk = 0; kk < 32; kk++) {
      const int kb = 16 * kk + 8 * hh;
      const float4 a0 = *(const float4*)&h_[(size_t)(row0 + l31) * CTRL + kb];
      const float4 a1 = *(const float4*)&h_[(size_t)(row0 + l31) * CTRL + kb + 4];
      const u32x4 av = {cvtpk(a0.x, a0.y), cvtpk(a0.z, a0.w), cvtpk(a1.x, a1.y), cvtpk(a1.z, a1.w)};
      const bf16x8 afr = __builtin_bit_cast(bf16x8, av);
#pragma unroll
      for (int ct = 0; ct < 2; ct++) {
        const bf16x8 bfr = *(const bf16x8*)&Wkt[(size_t)(32 * ct + l31) * IN_DIM + kb];
        acc[ct] = __builtin_amdgcn_mfma_f32_32x32x16_bf16(afr, bfr, acc[ct], 0, 0, 0);
      }
    }
    const float bk0 = bk[l31], bk1 = bk[32 + l31];
    float v0[16], v1[16], ss[16];
#pragma unroll
    for (int r = 0; r < 16; r++) {
      v0[r] = tanhf(acc[0][r] + bk0);
      v1[r] = tanhf(acc[1][r] + bk1);
      ss[r] = v0[r] * v0[r] + v1[r] * v1[r];
    }
#pragma unroll
    for (int off = 1; off < 32; off <<= 1)
#pragma unroll
      for (int r = 0; r < 16; r++) ss[r] += __shfl_xor(ss[r], off);
#pragma unroll
    for (int r = 0; r < 16; r++) {
      const float inv = 1.f / (sqrtf(ss[r]) + EPSV);
      const int row = row0 + (r & 3) + 8 * (r >> 2) + 4 * hh;
      kn_bf[(size_t)row * 64 + l31] = f2bf_hw(v0[r] * inv);
      kn_bf[(size_t)row * 64 + 32 + l31] = f2bf_hw(v1[r] * inv);
    }
  } else {
    __shared__ float red[4];
    out[2048 + t] = h_[(size_t)(B_SZ - 1) * CTRL + t];
    out[2048 + 256 + t] = h_[(size_t)(B_SZ - 1) * CTRL + 256 + t];
    float p = x[(size_t)(B_SZ - 1) * IN_DIM + t] * Wg[t] +
              x[(size_t)(B_SZ - 1) * IN_DIM + 256 + t] * Wg[256 + t];
#pragma unroll
    for (int off = 32; off >= 1; off >>= 1) p += __shfl_xor(p, off);
    if ((t & 63) == 0) red[t >> 6] = p;
    __syncthreads();
    if (t == 0) out[2048 + 512] = red[0] + red[1] + red[2] + red[3] + bg[0];
  }
}

// ---------------- Kernel E: fused attention partials ----------------
// grid (16, 64), 256 thr = 4 waves; wave w owns rows rb*128+32w..+31.
// kn B-frags persistent in regs; P A-frags via h-partner shfl exchange (no sP).
__global__ __launch_bounds__(256, 4) void k_attn(const unsigned short* __restrict__ kn_bf,
                                                 const unsigned short* __restrict__ Mn_t,
                                                 const unsigned short* __restrict__ Mt_t,
                                                 float* __restrict__ l_part,
                                                 unsigned short* __restrict__ r_bf,
                                                 float* __restrict__ wdump) {
  __shared__ __align__(16) unsigned short sMn[2][4096];
  __shared__ __align__(16) unsigned short sMt[2][4096];
  const int rb = blockIdx.x, sp = blockIdx.y;
  const int t = threadIdx.x, lane = t & 63, w = t >> 6;
  const int l31 = lane & 31, hh = lane >> 5, l7 = lane & 7;
  const int row0 = rb * 128 + 32 * w;

  // persistent kn B-frags: lane l31 = brow, k-elems d = 16kk+8h+j
  bf16x8 bq[4];
#pragma unroll
  for (int kk = 0; kk < 4; kk++)
    bq[kk] = *(const bf16x8*)&kn_bf[(size_t)(row0 + l31) * 64 + 16 * kk + 8 * hh];

  const int c0 = t, c1 = t + 256;
  const int r0 = c0 >> 3, d0 = r0 * 64 + (((c0 & 7) * 8) ^ ((r0 & 7) * 8));
  const int r1 = c1 >> 3, d1 = r1 * 64 + (((c1 & 7) * 8) ^ ((r1 & 7) * 8));
  {
    const size_t gb = (size_t)(sp * 16) * 4096;
    *(u16x8*)&sMn[0][d0] = *(const u16x8*)&Mn_t[gb + c0 * 8];
    *(u16x8*)&sMn[0][d1] = *(const u16x8*)&Mn_t[gb + c1 * 8];
    *(u16x8*)&sMt[0][d0] = *(const u16x8*)&Mt_t[gb + c0 * 8];
    *(u16x8*)&sMt[0][d1] = *(const u16x8*)&Mt_t[gb + c1 * 8];
  }
  __syncthreads();

  f32x16 Racc[2];
  Racc[0] = (f32x16)(0.f); Racc[1] = (f32x16)(0.f);
  float lrun = 0.f;

  u16x8 rn0, rn1, rt0, rt1;
  for (int it = 0; it < 16; ++it) {
    const int cur = it & 1;
    if (it < 15) {
      const size_t gn = (size_t)(sp * 16 + it + 1) * 4096;
      rn0 = *(const u16x8*)&Mn_t[gn + c0 * 8];
      rn1 = *(const u16x8*)&Mn_t[gn + c1 * 8];
      rt0 = *(const u16x8*)&Mt_t[gn + c0 * 8];
      rt1 = *(const u16x8*)&Mt_t[gn + c1 * 8];
    }

    // phase 1: S^T[loc][brow] = Mn . kn^T  (A from LDS, B from regs)
    f32x16 cst[2];
    cst[0] = (f32x16)(0.f); cst[1] = (f32x16)(0.f);
#pragma unroll
    for (int kk = 0; kk < 4; kk++) {
      const int koff = ((2 * kk + hh) ^ l7) * 8;
#pragma unroll
      for (int lt = 0; lt < 2; lt++) {
        const bf16x8 afr = *(const bf16x8*)&sMn[cur][(32 * lt + l31) * 64 + koff];
        cst[lt] = __builtin_amdgcn_mfma_f32_32x32x16_bf16(afr, bq[kk], cst[lt], 0, 0, 0);
      }
    }

    // softmax: p = exp2(s) (|s|<=~1.5, no max tracking)
#pragma unroll
    for (int lt = 0; lt < 2; lt++)
#pragma unroll
      for (int r = 0; r < 16; r++) {
        const float e = exp2_fast(cst[lt][r]);
        cst[lt][r] = e;
        lrun += e;
      }

    if (rb == 15 && w == 3 && l31 == 31) {  // batch row 2047: dump raw P
#pragma unroll
      for (int lt = 0; lt < 2; lt++)
#pragma unroll
        for (int rr = 0; rr < 4; rr++)
          *(float4*)&wdump[sp * 1024 + it * 64 + 32 * lt + 8 * rr + 4 * hh] =
              make_float4(cst[lt][4 * rr], cst[lt][4 * rr + 1], cst[lt][4 * rr + 2],
                          cst[lt][4 * rr + 3]);
    }

    // pack: pk[lt*8+rr*2+m] = bf16 pair at locs 32lt+8rr+4h+2m+{0,1}
    unsigned int pk[16];
#pragma unroll
    for (int lt = 0; lt < 2; lt++)
#pragma unroll
      for (int rr = 0; rr < 4; rr++) {
        pk[lt * 8 + rr * 2 + 0] = cvtpk(cst[lt][4 * rr + 0], cst[lt][4 * rr + 1]);
        pk[lt * 8 + rr * 2 + 1] = cvtpk(cst[lt][4 * rr + 2], cst[lt][4 * rr + 3]);
      }

    // phase 2: R[brow][d] += P @ Mt  (A via h-partner exchange, B from LDS)
#pragma unroll
    for (int kk = 0; kk < 4; kk++) {
      const int lt = kk >> 1;
      const int rrE = 2 * (kk & 1), rrO = rrE + 1;
      const unsigned int s0 = hh ? pk[lt * 8 + rrE * 2 + 0] : pk[lt * 8 + rrO * 2 + 0];
      const unsigned int s1 = hh ? pk[lt * 8 + rrE * 2 + 1] : pk[lt * 8 + rrO * 2 + 1];
      const unsigned int g0 = (unsigned int)__shfl_xor((int)s0, 32);
      const unsigned int g1 = (unsigned int)__shfl_xor((int)s1, 32);
      u32x4 aw;
      if (hh == 0)
        aw = (u32x4){pk[lt * 8 + rrE * 2 + 0], pk[lt * 8 + rrE * 2 + 1], g0, g1};
      else
        aw = (u32x4){g0, g1, pk[lt * 8 + rrO * 2 + 0], pk[lt * 8 + rrO * 2 + 1]};
      const bf16x8 afr = __builtin_bit_cast(bf16x8, aw);
      const int koff = ((2 * kk + hh) ^ l7) * 8;
#pragma unroll
      for (int dt = 0; dt < 2; dt++) {
        const bf16x8 bfr = *(const bf16x8*)&sMt[cur][(32 * dt + l31) * 64 + koff];
        Racc[dt] = __builtin_amdgcn_mfma_f32_32x32x16_bf16(afr, bfr, Racc[dt], 0, 0, 0);
      }
    }

    if (it < 15) {
      const int nxt = cur ^ 1;
      *(u16x8*)&sMn[nxt][d0] = rn0; *(u16x8*)&sMn[nxt][d1] = rn1;
      *(u16x8*)&sMt[nxt][d0] = rt0; *(u16x8*)&sMt[nxt][d1] = rt1;
    }
    __syncthreads();
  }

  lrun += __shfl_xor(lrun, 32);
  if (hh == 0) l_part[(size_t)(row0 + l31) * NSPLIT + sp] = lrun;

#pragma unroll
  for (int dt = 0; dt < 2; dt++)
#pragma unroll
    for (int r = 0; r < 16; r++) {
      const int brow = (r & 3) + 8 * (r >> 2) + 4 * hh;
      r_bf[((size_t)(row0 + brow) * NSPLIT + sp) * 64 + 32 * dt + l31] = f2bf_hw(Racc[dt][r]);
    }
}

// ---------------- Kernel F: combine + output dot / w_read divide ----------------
__global__ __launch_bounds__(256) void k_post(const float* __restrict__ l_part,
                                              const unsigned short* __restrict__ r_bf,
                                              const float* __restrict__ h,
                                              const float* __restrict__ Wout,
                                              const float* __restrict__ bout,
                                              const float* __restrict__ wdump,
                                              float* __restrict__ out) {
  const int lane = threadIdx.x & 63, w = threadIdx.x >> 6;
  const int bx = blockIdx.x;
  if (bx < 512) {
    const int row = bx * 4 + w;
    float l = l_part[(size_t)row * NSPLIT + lane];
#pragma unroll
    for (int off = 32; off >= 1; off >>= 1) l += __shfl_xor(l, off);
    float rd = 0.f;
    for (int sp2 = 0; sp2 < NSPLIT; sp2++)
      rd += bf2f(r_bf[((size_t)row * NSPLIT + sp2) * 64 + lane]);
    rd /= l;
    float acc = Wout[CTRL + lane] * rd;
    for (int k = lane; k < CTRL; k += 64) acc += h[(size_t)row * CTRL + k] * Wout[k];
#pragma unroll
    for (int off = 32; off >= 1; off >>= 1) acc += __shfl_xor(acc, off);
    if (lane == 0) out[row] = acc + bout[0];
  } else {
    float l = l_part[(size_t)(B_SZ - 1) * NSPLIT + lane];
#pragma unroll
    for (int off = 32; off >= 1; off >>= 1) l += __shfl_xor(l, off);
    const float rl = 1.f / l;
    const int i = ((bx - 512) * 256 + threadIdx.x) * 4;
    const float4 v = *(const float4*)&wdump[i];
    *(float4*)&out[2048 + 512 + 1 + i] = make_float4(v.x * rl, v.y * rl, v.z * rl, v.w * rl);
  }
}

extern "C" void kernel_launch(void* const* d_in, const int* in_sizes, int n_in,
                              void* d_out, int out_size, void* d_ws, size_t ws_size,
                              hipStream_t stream) {
  const float* x = (const float*)d_in[0];
  const float* Wh = (const float*)d_in[1];
  const float* bh = (const float*)d_in[2];
  const float* Wg = (const float*)d_in[3];
  const float* bg = (const float*)d_in[4];
  const float* Wk = (const float*)d_in[5];
  const float* bk = (const float*)d_in[6];
  const float* M = (const float*)d_in[7];
  const float* Wout = (const float*)d_in[8];
  const float* bout = (const float*)d_in[9];
  float* out = (float*)d_out;

  float* ws = (float*)d_ws;
  float* h = ws;                                   // 1,048,576 f (4 MB)
  float* l_part = h + 1048576;                     // 2048*64 = 131,072 f
  float* wdump = l_part + 131072;                  // 65,536 f
  unsigned short* r_bf = (unsigned short*)(wdump + 65536);  // 2048*64*64 us (16 MB)
  unsigned short* kn_bf = r_bf + 8388608;          // 131,072 us
  unsigned short* Mn_t = kn_bf + 131072;           // 4,194,304 us (8 MB)
  unsigned short* Mt_t = Mn_t + 4194304;           // 4,194,304 us (8 MB)
  unsigned short* xb = Mt_t + 4194304;             // 1,048,576 us (2 MB)
  unsigned short* Wht = xb + 1048576;              // 262,144 us
  unsigned short* Wkt = Wht + 262144;              // 32,768 us  (total ~39.6 MB)

  hipLaunchKernelGGL(k_prep_all, dim3(1608), dim3(256), 0, stream,
                     x, Wh, Wk, M, xb, Wht, Wkt, Mn_t, Mt_t);
  hipLaunchKernelGGL(k_hgemm, dim3(32, 4), dim3(256), 0, stream, xb, Wht, bh, h);
  hipLaunchKernelGGL(k_readkey, dim3(17), dim3(256), 0, stream,
                     h, Wkt, bk, x, Wg, bg, kn_bf, out);
  hipLaunchKernelGGL(k_attn, dim3(16, NSPLIT), dim3(256), 0, stream,
                     kn_bf, Mn_t, Mt_t, l_part, r_bf, wdump);
  hipLaunchKernelGGL(k_post, dim3(512 + 64), dim3(256), 0, stream,
                     l_part, r_bf, h, Wout, bout, wdump, out);
}

// Round 6
// 87.486 us; speedup vs baseline: 12.5816x; 1.2512x over previous
//
#include <hip/hip_runtime.h>

#define B_SZ 2048
#define IN_DIM 512
#define CTRL 512
#define N_LOC 65536
#define NSPLIT 64
#define LPS (N_LOC / NSPLIT)   // 1024 locs per split, 16 tiles of 64
#define EPSV 1e-8f
#define LOG2E 1.4426950408889634f

typedef __attribute__((ext_vector_type(8))) short bf16x8;
typedef __attribute__((ext_vector_type(4))) float f32x4;
typedef __attribute__((ext_vector_type(16))) float f32x16;
typedef __attribute__((ext_vector_type(4))) unsigned int u32x4;
typedef __attribute__((ext_vector_type(8))) unsigned short u16x8;

static __device__ __forceinline__ unsigned int cvtpk(float lo, float hi) {
  unsigned int r;
  asm("v_cvt_pk_bf16_f32 %0, %1, %2" : "=v"(r) : "v"(lo), "v"(hi));
  return r;
}
static __device__ __forceinline__ unsigned short f2bf_hw(float f) {
  return (unsigned short)(cvtpk(f, f) & 0xffffu);
}
static __device__ __forceinline__ float bf2f(unsigned short u) {
  return __builtin_bit_cast(float, ((unsigned int)u) << 16);
}
static __device__ __forceinline__ float exp2_fast(float x) {
  float r;
  asm("v_exp_f32 %0, %1" : "=v"(r) : "v"(x));
  return r;
}

// ---------------- Kernel P: all preprocessing ----------------
__global__ __launch_bounds__(256) void k_prep_all(const float* __restrict__ x,
                                                  const float* __restrict__ Wh,
                                                  const float* __restrict__ Wk,
                                                  const float* __restrict__ M,
                                                  unsigned short* __restrict__ xb,
                                                  unsigned short* __restrict__ Wht,
                                                  unsigned short* __restrict__ Wkt,
                                                  unsigned short* __restrict__ Mn_t,
                                                  unsigned short* __restrict__ Mt_t) {
  const int bx = blockIdx.x, t = threadIdx.x;
  if (bx < 512) {
    const int base = bx * 2048 + t * 8;
    const float4 a = *(const float4*)&x[base];
    const float4 b = *(const float4*)&x[base + 4];
    u16x8 o;
    unsigned int u0 = cvtpk(a.x, a.y), u1 = cvtpk(a.z, a.w);
    unsigned int u2 = cvtpk(b.x, b.y), u3 = cvtpk(b.z, b.w);
    o[0] = (unsigned short)u0; o[1] = (unsigned short)(u0 >> 16);
    o[2] = (unsigned short)u1; o[3] = (unsigned short)(u1 >> 16);
    o[4] = (unsigned short)u2; o[5] = (unsigned short)(u2 >> 16);
    o[6] = (unsigned short)u3; o[7] = (unsigned short)(u3 >> 16);
    *(u16x8*)&xb[base] = o;
  } else if (bx < 584) {
    __shared__ float ld[64][65];
    const bool isWh = bx < 576;
    const int id = isWh ? bx - 512 : bx - 576;
    const int ti = isWh ? (id >> 3) : id;
    const int tj = isWh ? (id & 7) : 0;
    const int ncol = isWh ? CTRL : 64;
    const float* src = isWh ? Wh : Wk;
#pragma unroll
    for (int i = 0; i < 4; i++) {
      const int c = t + i * 256;
      const int r = c >> 4, c4 = (c & 15) * 4;
      const float4 v = *(const float4*)&src[(size_t)(ti * 64 + r) * ncol + tj * 64 + c4];
      ld[r][c4] = v.x; ld[r][c4 + 1] = v.y; ld[r][c4 + 2] = v.z; ld[r][c4 + 3] = v.w;
    }
    __syncthreads();
    unsigned short* dst = isWh ? Wht : Wkt;
#pragma unroll
    for (int i = 0; i < 2; i++) {
      const int c = t + i * 256;
      const int col = c >> 3, k8 = (c & 7) * 8;
      u16x8 o;
#pragma unroll
      for (int j = 0; j < 4; j++) {
        unsigned int u = cvtpk(ld[k8 + 2 * j][col], ld[k8 + 2 * j + 1][col]);
        o[2 * j] = (unsigned short)u;
        o[2 * j + 1] = (unsigned short)(u >> 16);
      }
      *(u16x8*)&dst[(size_t)(tj * 64 + col) * IN_DIM + ti * 64 + k8] = o;
    }
  } else {
    const int b = bx - 584;
    const int c4 = t & 15, lg = t >> 4;
    float vv[4][4], ss[4];
#pragma unroll
    for (int r = 0; r < 4; r++) {
      const int loc = b * 64 + lg * 4 + r;
      const float4 f = *(const float4*)&M[(size_t)loc * 64 + c4 * 4];
      vv[r][0] = f.x; vv[r][1] = f.y; vv[r][2] = f.z; vv[r][3] = f.w;
      ss[r] = f.x * f.x + f.y * f.y + f.z * f.z + f.w * f.w;
    }
#pragma unroll
    for (int r = 0; r < 4; r++)
#pragma unroll
      for (int off = 1; off < 16; off <<= 1) ss[r] += __shfl_xor(ss[r], off);
#pragma unroll
    for (int r = 0; r < 4; r++) {
      const float s = (1.f / (sqrtf(ss[r]) + EPSV)) * LOG2E;
      uint2 u;
      u.x = cvtpk(vv[r][0] * s, vv[r][1] * s);
      u.y = cvtpk(vv[r][2] * s, vv[r][3] * s);
      *(uint2*)&Mn_t[(size_t)b * 4096 + (lg * 4 + r) * 64 + c4 * 4] = u;
    }
#pragma unroll
    for (int j = 0; j < 4; j++) {
      uint2 u;
      u.x = cvtpk(vv[0][j], vv[1][j]);
      u.y = cvtpk(vv[2][j], vv[3][j]);
      *(uint2*)&Mt_t[(size_t)b * 4096 + (c4 * 4 + j) * 64 + lg * 4] = u;
    }
  }
}

// ---------------- Kernel A: h = tanh(x @ W_h + b_h), bf16 MFMA ----------------
// grid (32, 8): 64x64 tile, 256 thr = 4 waves; wave w owns cols 16w..16w+15.
__global__ __launch_bounds__(256) void k_hgemm(const unsigned short* __restrict__ xb,
                                               const unsigned short* __restrict__ Wht,
                                               const float* __restrict__ bh,
                                               float* __restrict__ h) {
  __shared__ __align__(16) unsigned short xs[64 * 32];
  __shared__ __align__(16) unsigned short wsb[64 * 32];
  const int t = threadIdx.x, lane = t & 63, w = t >> 6, lo = lane & 15, g = lane >> 4;
  const int bm = blockIdx.x * 64, bn = blockIdx.y * 64;
  f32x4 acc[4];
#pragma unroll
  for (int rt = 0; rt < 4; rt++) acc[rt] = (f32x4){0.f, 0.f, 0.f, 0.f};

  for (int k0 = 0; k0 < IN_DIM; k0 += 32) {
    {
      const int r = t >> 2, k8 = (t & 3) * 8;
      *(u16x8*)&xs[r * 32 + (k8 ^ ((r & 3) * 8))] =
          *(const u16x8*)&xb[(size_t)(bm + r) * IN_DIM + k0 + k8];
      *(u16x8*)&wsb[r * 32 + (k8 ^ ((r & 3) * 8))] =
          *(const u16x8*)&Wht[(size_t)(bn + r) * IN_DIM + k0 + k8];
    }
    __syncthreads();
    const int koff = (8 * g) ^ ((lo & 3) * 8);
    const bf16x8 bfr = *(const bf16x8*)&wsb[(16 * w + lo) * 32 + koff];
#pragma unroll
    for (int rt = 0; rt < 4; rt++) {
      const bf16x8 afr = *(const bf16x8*)&xs[(16 * rt + lo) * 32 + koff];
      acc[rt] = __builtin_amdgcn_mfma_f32_16x16x32_bf16(afr, bfr, acc[rt], 0, 0, 0);
    }
    __syncthreads();
  }
  const int col = bn + 16 * w + lo;
  const float b = bh[col];
#pragma unroll
  for (int rt = 0; rt < 4; rt++)
#pragma unroll
    for (int q = 0; q < 4; q++) {
      const int row = bm + 16 * rt + 4 * g + q;
      h[(size_t)row * CTRL + col] = tanhf(acc[rt][q] + b);
    }
}

// ---------------- Kernel C: read-key, 64 blocks x 32 rows, 4-wave k-split ----------------
__global__ __launch_bounds__(256) void k_readkey(const float* __restrict__ h_,
                                                 const unsigned short* __restrict__ Wkt,
                                                 const float* __restrict__ bk,
                                                 const float* __restrict__ x,
                                                 const float* __restrict__ Wg,
                                                 const float* __restrict__ bg,
                                                 unsigned short* __restrict__ kn_bf,
                                                 float* __restrict__ out) {
  __shared__ float sAcc[4][32][65];
  __shared__ float red[4];
  const int t = threadIdx.x, lane = t & 63, w = t >> 6;
  const int l31 = lane & 31, hh = lane >> 5;
  if (blockIdx.x < 64) {
    const int row0 = blockIdx.x * 32;
    f32x16 acc[2];
    acc[0] = (f32x16)(0.f); acc[1] = (f32x16)(0.f);
    // wave w covers k in [128w, 128w+128)
#pragma unroll
    for (int kk = 0; kk < 8; kk++) {
      const int kb = 128 * w + 16 * kk + 8 * hh;
      const float4 a0 = *(const float4*)&h_[(size_t)(row0 + l31) * CTRL + kb];
      const float4 a1 = *(const float4*)&h_[(size_t)(row0 + l31) * CTRL + kb + 4];
      const u32x4 av = {cvtpk(a0.x, a0.y), cvtpk(a0.z, a0.w), cvtpk(a1.x, a1.y), cvtpk(a1.z, a1.w)};
      const bf16x8 afr = __builtin_bit_cast(bf16x8, av);
#pragma unroll
      for (int ct = 0; ct < 2; ct++) {
        const bf16x8 bfr = *(const bf16x8*)&Wkt[(size_t)(32 * ct + l31) * IN_DIM + kb];
        acc[ct] = __builtin_amdgcn_mfma_f32_32x32x16_bf16(afr, bfr, acc[ct], 0, 0, 0);
      }
    }
#pragma unroll
    for (int ct = 0; ct < 2; ct++)
#pragma unroll
      for (int r = 0; r < 16; r++)
        sAcc[w][(r & 3) + 8 * (r >> 2) + 4 * hh][32 * ct + l31] = acc[ct][r];
    __syncthreads();
    const int row = t >> 3, c8 = (t & 7) * 8;
    float v[8];
    float ss = 0.f;
#pragma unroll
    for (int j = 0; j < 8; j++) {
      const float s = sAcc[0][row][c8 + j] + sAcc[1][row][c8 + j] +
                      sAcc[2][row][c8 + j] + sAcc[3][row][c8 + j] + bk[c8 + j];
      v[j] = tanhf(s);
      ss += v[j] * v[j];
    }
    ss += __shfl_xor(ss, 1);
    ss += __shfl_xor(ss, 2);
    ss += __shfl_xor(ss, 4);
    const float inv = 1.f / (sqrtf(ss) + EPSV);
    u16x8 o;
#pragma unroll
    for (int j = 0; j < 4; j++) {
      const unsigned int u = cvtpk(v[2 * j] * inv, v[2 * j + 1] * inv);
      o[2 * j] = (unsigned short)u;
      o[2 * j + 1] = (unsigned short)(u >> 16);
    }
    *(u16x8*)&kn_bf[(size_t)(row0 + row) * 64 + c8] = o;
  } else {
    out[2048 + t] = h_[(size_t)(B_SZ - 1) * CTRL + t];
    out[2048 + 256 + t] = h_[(size_t)(B_SZ - 1) * CTRL + 256 + t];
    float p = x[(size_t)(B_SZ - 1) * IN_DIM + t] * Wg[t] +
              x[(size_t)(B_SZ - 1) * IN_DIM + 256 + t] * Wg[256 + t];
#pragma unroll
    for (int off = 32; off >= 1; off >>= 1) p += __shfl_xor(p, off);
    if ((t & 63) == 0) red[t >> 6] = p;
    __syncthreads();
    if (t == 0) out[2048 + 512] = red[0] + red[1] + red[2] + red[3] + bg[0];
  }
}

// ---------------- Kernel E: fused attention partials ----------------
// grid (NSPLIT=64, 16): sp = blockIdx.x -> XCD = sp&7 (L2-pins each split's M).
// 256 thr = 4 waves; wave w owns rows rb*128+32w..+31.
__global__ __launch_bounds__(256, 4) void k_attn(const unsigned short* __restrict__ kn_bf,
                                                 const unsigned short* __restrict__ Mn_t,
                                                 const unsigned short* __restrict__ Mt_t,
                                                 float* __restrict__ l_part,
                                                 unsigned short* __restrict__ r_bf,
                                                 float* __restrict__ wdump) {
  __shared__ __align__(16) unsigned short sMn[2][4096];
  __shared__ __align__(16) unsigned short sMt[2][4096];
  const int sp = blockIdx.x, rb = blockIdx.y;
  const int t = threadIdx.x, lane = t & 63, w = t >> 6;
  const int l31 = lane & 31, hh = lane >> 5, l7 = lane & 7;
  const int row0 = rb * 128 + 32 * w;

  bf16x8 bq[4];
#pragma unroll
  for (int kk = 0; kk < 4; kk++)
    bq[kk] = *(const bf16x8*)&kn_bf[(size_t)(row0 + l31) * 64 + 16 * kk + 8 * hh];

  const int c0 = t, c1 = t + 256;
  const int r0 = c0 >> 3, d0 = r0 * 64 + (((c0 & 7) * 8) ^ ((r0 & 7) * 8));
  const int r1 = c1 >> 3, d1 = r1 * 64 + (((c1 & 7) * 8) ^ ((r1 & 7) * 8));
  {
    const size_t gb = (size_t)(sp * 16) * 4096;
    *(u16x8*)&sMn[0][d0] = *(const u16x8*)&Mn_t[gb + c0 * 8];
    *(u16x8*)&sMn[0][d1] = *(const u16x8*)&Mn_t[gb + c1 * 8];
    *(u16x8*)&sMt[0][d0] = *(const u16x8*)&Mt_t[gb + c0 * 8];
    *(u16x8*)&sMt[0][d1] = *(const u16x8*)&Mt_t[gb + c1 * 8];
  }
  __syncthreads();

  f32x16 Racc[2];
  Racc[0] = (f32x16)(0.f); Racc[1] = (f32x16)(0.f);
  float lrun = 0.f;

  u16x8 rn0, rn1, rt0, rt1;
  for (int it = 0; it < 16; ++it) {
    const int cur = it & 1;
    if (it < 15) {
      const size_t gn = (size_t)(sp * 16 + it + 1) * 4096;
      rn0 = *(const u16x8*)&Mn_t[gn + c0 * 8];
      rn1 = *(const u16x8*)&Mn_t[gn + c1 * 8];
      rt0 = *(const u16x8*)&Mt_t[gn + c0 * 8];
      rt1 = *(const u16x8*)&Mt_t[gn + c1 * 8];
    }

    // phase 1: S^T[loc][brow] = Mn . kn^T
    f32x16 cst[2];
    cst[0] = (f32x16)(0.f); cst[1] = (f32x16)(0.f);
    __builtin_amdgcn_s_setprio(1);
#pragma unroll
    for (int kk = 0; kk < 4; kk++) {
      const int koff = ((2 * kk + hh) ^ l7) * 8;
#pragma unroll
      for (int lt = 0; lt < 2; lt++) {
        const bf16x8 afr = *(const bf16x8*)&sMn[cur][(32 * lt + l31) * 64 + koff];
        cst[lt] = __builtin_amdgcn_mfma_f32_32x32x16_bf16(afr, bq[kk], cst[lt], 0, 0, 0);
      }
    }
    __builtin_amdgcn_s_setprio(0);

    // softmax: p = exp2(s), no max tracking (|s| <= ~1.5)
#pragma unroll
    for (int lt = 0; lt < 2; lt++)
#pragma unroll
      for (int r = 0; r < 16; r++) {
        const float e = exp2_fast(cst[lt][r]);
        cst[lt][r] = e;
        lrun += e;
      }

    if (rb == 15 && w == 3 && l31 == 31) {  // batch row 2047: dump raw P
#pragma unroll
      for (int lt = 0; lt < 2; lt++)
#pragma unroll
        for (int rr = 0; rr < 4; rr++)
          *(float4*)&wdump[sp * 1024 + it * 64 + 32 * lt + 8 * rr + 4 * hh] =
              make_float4(cst[lt][4 * rr], cst[lt][4 * rr + 1], cst[lt][4 * rr + 2],
                          cst[lt][4 * rr + 3]);
    }

    unsigned int pk[16];
#pragma unroll
    for (int lt = 0; lt < 2; lt++)
#pragma unroll
      for (int rr = 0; rr < 4; rr++) {
        pk[lt * 8 + rr * 2 + 0] = cvtpk(cst[lt][4 * rr + 0], cst[lt][4 * rr + 1]);
        pk[lt * 8 + rr * 2 + 1] = cvtpk(cst[lt][4 * rr + 2], cst[lt][4 * rr + 3]);
      }

    // phase 2: R[brow][d] += P @ Mt
#pragma unroll
    for (int kk = 0; kk < 4; kk++) {
      const int lt = kk >> 1;
      const int rrE = 2 * (kk & 1), rrO = rrE + 1;
      const unsigned int s0 = hh ? pk[lt * 8 + rrE * 2 + 0] : pk[lt * 8 + rrO * 2 + 0];
      const unsigned int s1 = hh ? pk[lt * 8 + rrE * 2 + 1] : pk[lt * 8 + rrO * 2 + 1];
      const unsigned int g0 = (unsigned int)__shfl_xor((int)s0, 32);
      const unsigned int g1 = (unsigned int)__shfl_xor((int)s1, 32);
      u32x4 aw;
      if (hh == 0)
        aw = (u32x4){pk[lt * 8 + rrE * 2 + 0], pk[lt * 8 + rrE * 2 + 1], g0, g1};
      else
        aw = (u32x4){g0, g1, pk[lt * 8 + rrO * 2 + 0], pk[lt * 8 + rrO * 2 + 1]};
      const bf16x8 afr = __builtin_bit_cast(bf16x8, aw);
      const int koff = ((2 * kk + hh) ^ l7) * 8;
      __builtin_amdgcn_s_setprio(1);
#pragma unroll
      for (int dt = 0; dt < 2; dt++) {
        const bf16x8 bfr = *(const bf16x8*)&sMt[cur][(32 * dt + l31) * 64 + koff];
        Racc[dt] = __builtin_amdgcn_mfma_f32_32x32x16_bf16(afr, bfr, Racc[dt], 0, 0, 0);
      }
      __builtin_amdgcn_s_setprio(0);
    }

    if (it < 15) {
      const int nxt = cur ^ 1;
      *(u16x8*)&sMn[nxt][d0] = rn0; *(u16x8*)&sMn[nxt][d1] = rn1;
      *(u16x8*)&sMt[nxt][d0] = rt0; *(u16x8*)&sMt[nxt][d1] = rt1;
    }
    __syncthreads();
  }

  lrun += __shfl_xor(lrun, 32);
  if (hh == 0) l_part[(size_t)(row0 + l31) * NSPLIT + sp] = lrun;

#pragma unroll
  for (int dt = 0; dt < 2; dt++)
#pragma unroll
    for (int r = 0; r < 16; r++) {
      const int brow = (r & 3) + 8 * (r >> 2) + 4 * hh;
      r_bf[((size_t)(row0 + brow) * NSPLIT + sp) * 64 + 32 * dt + l31] = f2bf_hw(Racc[dt][r]);
    }
}

// ---------------- Kernel F: combine + output dot / w_read divide ----------------
__global__ __launch_bounds__(256) void k_post(const float* __restrict__ l_part,
                                              const unsigned short* __restrict__ r_bf,
                                              const float* __restrict__ h,
                                              const float* __restrict__ Wout,
                                              const float* __restrict__ bout,
                                              const float* __restrict__ wdump,
                                              float* __restrict__ out) {
  const int lane = threadIdx.x & 63, w = threadIdx.x >> 6;
  const int bx = blockIdx.x;
  if (bx < 512) {
    const int row = bx * 4 + w;
    float l = l_part[(size_t)row * NSPLIT + lane];
#pragma unroll
    for (int off = 32; off >= 1; off >>= 1) l += __shfl_xor(l, off);
    float rd = 0.f;
    for (int sp2 = 0; sp2 < NSPLIT; sp2++)
      rd += bf2f(r_bf[((size_t)row * NSPLIT + sp2) * 64 + lane]);
    rd /= l;
    float acc = Wout[CTRL + lane] * rd;
    for (int k = lane; k < CTRL; k += 64) acc += h[(size_t)row * CTRL + k] * Wout[k];
#pragma unroll
    for (int off = 32; off >= 1; off >>= 1) acc += __shfl_xor(acc, off);
    if (lane == 0) out[row] = acc + bout[0];
  } else {
    float l = l_part[(size_t)(B_SZ - 1) * NSPLIT + lane];
#pragma unroll
    for (int off = 32; off >= 1; off >>= 1) l += __shfl_xor(l, off);
    const float rl = 1.f / l;
    const int i = ((bx - 512) * 256 + threadIdx.x) * 4;
    const float4 v = *(const float4*)&wdump[i];
    *(float4*)&out[2048 + 512 + 1 + i] = make_float4(v.x * rl, v.y * rl, v.z * rl, v.w * rl);
  }
}

extern "C" void kernel_launch(void* const* d_in, const int* in_sizes, int n_in,
                              void* d_out, int out_size, void* d_ws, size_t ws_size,
                              hipStream_t stream) {
  const float* x = (const float*)d_in[0];
  const float* Wh = (const float*)d_in[1];
  const float* bh = (const float*)d_in[2];
  const float* Wg = (const float*)d_in[3];
  const float* bg = (const float*)d_in[4];
  const float* Wk = (const float*)d_in[5];
  const float* bk = (const float*)d_in[6];
  const float* M = (const float*)d_in[7];
  const float* Wout = (const float*)d_in[8];
  const float* bout = (const float*)d_in[9];
  float* out = (float*)d_out;

  float* ws = (float*)d_ws;
  float* h = ws;                                   // 1,048,576 f (4 MB)
  float* l_part = h + 1048576;                     // 131,072 f
  float* wdump = l_part + 131072;                  // 65,536 f
  unsigned short* r_bf = (unsigned short*)(wdump + 65536);  // 8,388,608 us (16 MB)
  unsigned short* kn_bf = r_bf + 8388608;          // 131,072 us
  unsigned short* Mn_t = kn_bf + 131072;           // 4,194,304 us (8 MB)
  unsigned short* Mt_t = Mn_t + 4194304;           // 4,194,304 us (8 MB)
  unsigned short* xb = Mt_t + 4194304;             // 1,048,576 us (2 MB)
  unsigned short* Wht = xb + 1048576;              // 262,144 us
  unsigned short* Wkt = Wht + 262144;              // 32,768 us  (total ~39.6 MB)

  hipLaunchKernelGGL(k_prep_all, dim3(1608), dim3(256), 0, stream,
                     x, Wh, Wk, M, xb, Wht, Wkt, Mn_t, Mt_t);
  hipLaunchKernelGGL(k_hgemm, dim3(32, 8), dim3(256), 0, stream, xb, Wht, bh, h);
  hipLaunchKernelGGL(k_readkey, dim3(65), dim3(256), 0, stream,
                     h, Wkt, bk, x, Wg, bg, kn_bf, out);
  hipLaunchKernelGGL(k_attn, dim3(NSPLIT, 16), dim3(256), 0, stream,
                     kn_bf, Mn_t, Mt_t, l_part, r_bf, wdump);
  hipLaunchKernelGGL(k_post, dim3(512 + 64), dim3(256), 0, stream,
                     l_part, r_bf, h, Wout, bout, wdump, out);
}

// Round 7
// 79.138 us; speedup vs baseline: 13.9087x; 1.1055x over previous
//
#include <hip/hip_runtime.h>

#define B_SZ 2048
#define IN_DIM 512
#define CTRL 512
#define N_LOC 65536
#define NSPLIT 64
#define LPS (N_LOC / NSPLIT)   // 1024 locs per split, 16 tiles of 64
#define EPSV 1e-8f
#define LOG2E 1.4426950408889634f

typedef __attribute__((ext_vector_type(8))) short bf16x8;
typedef __attribute__((ext_vector_type(4))) float f32x4;
typedef __attribute__((ext_vector_type(16))) float f32x16;
typedef __attribute__((ext_vector_type(4))) unsigned int u32x4;
typedef __attribute__((ext_vector_type(8))) unsigned short u16x8;

static __device__ __forceinline__ unsigned int cvtpk(float lo, float hi) {
  unsigned int r;
  asm("v_cvt_pk_bf16_f32 %0, %1, %2" : "=v"(r) : "v"(lo), "v"(hi));
  return r;
}
static __device__ __forceinline__ unsigned short f2bf_hw(float f) {
  return (unsigned short)(cvtpk(f, f) & 0xffffu);
}
static __device__ __forceinline__ float bf2f(unsigned short u) {
  return __builtin_bit_cast(float, ((unsigned int)u) << 16);
}
static __device__ __forceinline__ float exp2_fast(float x) {
  float r;
  asm("v_exp_f32 %0, %1" : "=v"(r) : "v"(x));
  return r;
}

// ---------------- Kernel P: all preprocessing ----------------
__global__ __launch_bounds__(256) void k_prep_all(const float* __restrict__ x,
                                                  const float* __restrict__ Wh,
                                                  const float* __restrict__ Wk,
                                                  const float* __restrict__ M,
                                                  unsigned short* __restrict__ xb,
                                                  unsigned short* __restrict__ Wht,
                                                  unsigned short* __restrict__ Wkt,
                                                  unsigned short* __restrict__ Mn_t,
                                                  unsigned short* __restrict__ Mt_t) {
  const int bx = blockIdx.x, t = threadIdx.x;
  if (bx < 512) {
    const int base = bx * 2048 + t * 8;
    const float4 a = *(const float4*)&x[base];
    const float4 b = *(const float4*)&x[base + 4];
    u16x8 o;
    unsigned int u0 = cvtpk(a.x, a.y), u1 = cvtpk(a.z, a.w);
    unsigned int u2 = cvtpk(b.x, b.y), u3 = cvtpk(b.z, b.w);
    o[0] = (unsigned short)u0; o[1] = (unsigned short)(u0 >> 16);
    o[2] = (unsigned short)u1; o[3] = (unsigned short)(u1 >> 16);
    o[4] = (unsigned short)u2; o[5] = (unsigned short)(u2 >> 16);
    o[6] = (unsigned short)u3; o[7] = (unsigned short)(u3 >> 16);
    *(u16x8*)&xb[base] = o;
  } else if (bx < 584) {
    __shared__ float ld[64][65];
    const bool isWh = bx < 576;
    const int id = isWh ? bx - 512 : bx - 576;
    const int ti = isWh ? (id >> 3) : id;
    const int tj = isWh ? (id & 7) : 0;
    const int ncol = isWh ? CTRL : 64;
    const float* src = isWh ? Wh : Wk;
#pragma unroll
    for (int i = 0; i < 4; i++) {
      const int c = t + i * 256;
      const int r = c >> 4, c4 = (c & 15) * 4;
      const float4 v = *(const float4*)&src[(size_t)(ti * 64 + r) * ncol + tj * 64 + c4];
      ld[r][c4] = v.x; ld[r][c4 + 1] = v.y; ld[r][c4 + 2] = v.z; ld[r][c4 + 3] = v.w;
    }
    __syncthreads();
    unsigned short* dst = isWh ? Wht : Wkt;
#pragma unroll
    for (int i = 0; i < 2; i++) {
      const int c = t + i * 256;
      const int col = c >> 3, k8 = (c & 7) * 8;
      u16x8 o;
#pragma unroll
      for (int j = 0; j < 4; j++) {
        unsigned int u = cvtpk(ld[k8 + 2 * j][col], ld[k8 + 2 * j + 1][col]);
        o[2 * j] = (unsigned short)u;
        o[2 * j + 1] = (unsigned short)(u >> 16);
      }
      *(u16x8*)&dst[(size_t)(tj * 64 + col) * IN_DIM + ti * 64 + k8] = o;
    }
  } else {
    const int b = bx - 584;
    const int c4 = t & 15, lg = t >> 4;
    float vv[4][4], ss[4];
#pragma unroll
    for (int r = 0; r < 4; r++) {
      const int loc = b * 64 + lg * 4 + r;
      const float4 f = *(const float4*)&M[(size_t)loc * 64 + c4 * 4];
      vv[r][0] = f.x; vv[r][1] = f.y; vv[r][2] = f.z; vv[r][3] = f.w;
      ss[r] = f.x * f.x + f.y * f.y + f.z * f.z + f.w * f.w;
    }
#pragma unroll
    for (int r = 0; r < 4; r++)
#pragma unroll
      for (int off = 1; off < 16; off <<= 1) ss[r] += __shfl_xor(ss[r], off);
#pragma unroll
    for (int r = 0; r < 4; r++) {
      const float s = (1.f / (sqrtf(ss[r]) + EPSV)) * LOG2E;
      uint2 u;
      u.x = cvtpk(vv[r][0] * s, vv[r][1] * s);
      u.y = cvtpk(vv[r][2] * s, vv[r][3] * s);
      *(uint2*)&Mn_t[(size_t)b * 4096 + (lg * 4 + r) * 64 + c4 * 4] = u;
    }
#pragma unroll
    for (int j = 0; j < 4; j++) {
      uint2 u;
      u.x = cvtpk(vv[0][j], vv[1][j]);
      u.y = cvtpk(vv[2][j], vv[3][j]);
      *(uint2*)&Mt_t[(size_t)b * 4096 + (c4 * 4 + j) * 64 + lg * 4] = u;
    }
  }
}

// ---------------- Kernel A: h = tanh(x @ W_h + b_h), bf16 MFMA ----------------
__global__ __launch_bounds__(256) void k_hgemm(const unsigned short* __restrict__ xb,
                                               const unsigned short* __restrict__ Wht,
                                               const float* __restrict__ bh,
                                               float* __restrict__ h) {
  __shared__ __align__(16) unsigned short xs[64 * 32];
  __shared__ __align__(16) unsigned short wsb[64 * 32];
  const int t = threadIdx.x, lane = t & 63, w = t >> 6, lo = lane & 15, g = lane >> 4;
  const int bm = blockIdx.x * 64, bn = blockIdx.y * 64;
  f32x4 acc[4];
#pragma unroll
  for (int rt = 0; rt < 4; rt++) acc[rt] = (f32x4){0.f, 0.f, 0.f, 0.f};

  for (int k0 = 0; k0 < IN_DIM; k0 += 32) {
    {
      const int r = t >> 2, k8 = (t & 3) * 8;
      *(u16x8*)&xs[r * 32 + (k8 ^ ((r & 3) * 8))] =
          *(const u16x8*)&xb[(size_t)(bm + r) * IN_DIM + k0 + k8];
      *(u16x8*)&wsb[r * 32 + (k8 ^ ((r & 3) * 8))] =
          *(const u16x8*)&Wht[(size_t)(bn + r) * IN_DIM + k0 + k8];
    }
    __syncthreads();
    const int koff = (8 * g) ^ ((lo & 3) * 8);
    const bf16x8 bfr = *(const bf16x8*)&wsb[(16 * w + lo) * 32 + koff];
#pragma unroll
    for (int rt = 0; rt < 4; rt++) {
      const bf16x8 afr = *(const bf16x8*)&xs[(16 * rt + lo) * 32 + koff];
      acc[rt] = __builtin_amdgcn_mfma_f32_16x16x32_bf16(afr, bfr, acc[rt], 0, 0, 0);
    }
    __syncthreads();
  }
  const int col = bn + 16 * w + lo;
  const float b = bh[col];
#pragma unroll
  for (int rt = 0; rt < 4; rt++)
#pragma unroll
    for (int q = 0; q < 4; q++) {
      const int row = bm + 16 * rt + 4 * g + q;
      h[(size_t)row * CTRL + col] = tanhf(acc[rt][q] + b);
    }
}

// ---------------- Kernel C: read-key, 64 blocks x 32 rows, 4-wave k-split ----------------
__global__ __launch_bounds__(256) void k_readkey(const float* __restrict__ h_,
                                                 const unsigned short* __restrict__ Wkt,
                                                 const float* __restrict__ bk,
                                                 const float* __restrict__ x,
                                                 const float* __restrict__ Wg,
                                                 const float* __restrict__ bg,
                                                 unsigned short* __restrict__ kn_bf,
                                                 float* __restrict__ out) {
  __shared__ float sAcc[4][32][65];
  __shared__ float red[4];
  const int t = threadIdx.x, lane = t & 63, w = t >> 6;
  const int l31 = lane & 31, hh = lane >> 5;
  if (blockIdx.x < 64) {
    const int row0 = blockIdx.x * 32;
    f32x16 acc[2];
    acc[0] = (f32x16)(0.f); acc[1] = (f32x16)(0.f);
#pragma unroll
    for (int kk = 0; kk < 8; kk++) {
      const int kb = 128 * w + 16 * kk + 8 * hh;
      const float4 a0 = *(const float4*)&h_[(size_t)(row0 + l31) * CTRL + kb];
      const float4 a1 = *(const float4*)&h_[(size_t)(row0 + l31) * CTRL + kb + 4];
      const u32x4 av = {cvtpk(a0.x, a0.y), cvtpk(a0.z, a0.w), cvtpk(a1.x, a1.y), cvtpk(a1.z, a1.w)};
      const bf16x8 afr = __builtin_bit_cast(bf16x8, av);
#pragma unroll
      for (int ct = 0; ct < 2; ct++) {
        const bf16x8 bfr = *(const bf16x8*)&Wkt[(size_t)(32 * ct + l31) * IN_DIM + kb];
        acc[ct] = __builtin_amdgcn_mfma_f32_32x32x16_bf16(afr, bfr, acc[ct], 0, 0, 0);
      }
    }
#pragma unroll
    for (int ct = 0; ct < 2; ct++)
#pragma unroll
      for (int r = 0; r < 16; r++)
        sAcc[w][(r & 3) + 8 * (r >> 2) + 4 * hh][32 * ct + l31] = acc[ct][r];
    __syncthreads();
    const int row = t >> 3, c8 = (t & 7) * 8;
    float v[8];
    float ss = 0.f;
#pragma unroll
    for (int j = 0; j < 8; j++) {
      const float s = sAcc[0][row][c8 + j] + sAcc[1][row][c8 + j] +
                      sAcc[2][row][c8 + j] + sAcc[3][row][c8 + j] + bk[c8 + j];
      v[j] = tanhf(s);
      ss += v[j] * v[j];
    }
    ss += __shfl_xor(ss, 1);
    ss += __shfl_xor(ss, 2);
    ss += __shfl_xor(ss, 4);
    const float inv = 1.f / (sqrtf(ss) + EPSV);
    u16x8 o;
#pragma unroll
    for (int j = 0; j < 4; j++) {
      const unsigned int u = cvtpk(v[2 * j] * inv, v[2 * j + 1] * inv);
      o[2 * j] = (unsigned short)u;
      o[2 * j + 1] = (unsigned short)(u >> 16);
    }
    *(u16x8*)&kn_bf[(size_t)(row0 + row) * 64 + c8] = o;
  } else {
    out[2048 + t] = h_[(size_t)(B_SZ - 1) * CTRL + t];
    out[2048 + 256 + t] = h_[(size_t)(B_SZ - 1) * CTRL + 256 + t];
    float p = x[(size_t)(B_SZ - 1) * IN_DIM + t] * Wg[t] +
              x[(size_t)(B_SZ - 1) * IN_DIM + 256 + t] * Wg[256 + t];
#pragma unroll
    for (int off = 32; off >= 1; off >>= 1) p += __shfl_xor(p, off);
    if ((t & 63) == 0) red[t >> 6] = p;
    __syncthreads();
    if (t == 0) out[2048 + 512] = red[0] + red[1] + red[2] + red[3] + bg[0];
  }
}

// ---------------- Kernel E: fused attention partials, 64 rows/wave ----------------
// grid (NSPLIT=64, 8): sp = blockIdx.x -> XCD = sp&7. 256 thr = 4 waves,
// wave w owns batch rows rb*256+64w .. +63 (2 rowsets of 32).
// P exchange across lane-halves via v_permlane32_swap (no LDS, no selects).
__global__ __launch_bounds__(256, 2) void k_attn(const unsigned short* __restrict__ kn_bf,
                                                 const unsigned short* __restrict__ Mn_t,
                                                 const unsigned short* __restrict__ Mt_t,
                                                 float* __restrict__ l_part,
                                                 unsigned short* __restrict__ r_bf,
                                                 float* __restrict__ wdump) {
  __shared__ __align__(16) unsigned short sMn[2][4096];
  __shared__ __align__(16) unsigned short sMt[2][4096];
  const int sp = blockIdx.x, rb = blockIdx.y;
  const int t = threadIdx.x, lane = t & 63, w = t >> 6;
  const int l31 = lane & 31, hh = lane >> 5, l7 = lane & 7;
  const int row0 = rb * 256 + 64 * w;

  // persistent kn B-frags for both rowsets
  bf16x8 bq[2][4];
#pragma unroll
  for (int rs = 0; rs < 2; rs++)
#pragma unroll
    for (int kk = 0; kk < 4; kk++)
      bq[rs][kk] =
          *(const bf16x8*)&kn_bf[(size_t)(row0 + 32 * rs + l31) * 64 + 16 * kk + 8 * hh];

  const int c0 = t, c1 = t + 256;
  const int r0 = c0 >> 3, d0 = r0 * 64 + (((c0 & 7) * 8) ^ ((r0 & 7) * 8));
  const int r1 = c1 >> 3, d1 = r1 * 64 + (((c1 & 7) * 8) ^ ((r1 & 7) * 8));
  {
    const size_t gb = (size_t)(sp * 16) * 4096;
    *(u16x8*)&sMn[0][d0] = *(const u16x8*)&Mn_t[gb + c0 * 8];
    *(u16x8*)&sMn[0][d1] = *(const u16x8*)&Mn_t[gb + c1 * 8];
    *(u16x8*)&sMt[0][d0] = *(const u16x8*)&Mt_t[gb + c0 * 8];
    *(u16x8*)&sMt[0][d1] = *(const u16x8*)&Mt_t[gb + c1 * 8];
  }
  __syncthreads();

  f32x16 Racc[2][2];
#pragma unroll
  for (int rs = 0; rs < 2; rs++)
#pragma unroll
    for (int dt = 0; dt < 2; dt++) Racc[rs][dt] = (f32x16)(0.f);
  float lr0a = 0.f, lr0b = 0.f, lr1a = 0.f, lr1b = 0.f;

  u16x8 rn0, rn1, rt0, rt1;
  for (int it = 0; it < 16; ++it) {
    const int cur = it & 1;
    if (it < 15) {
      const size_t gn = (size_t)(sp * 16 + it + 1) * 4096;
      rn0 = *(const u16x8*)&Mn_t[gn + c0 * 8];
      rn1 = *(const u16x8*)&Mn_t[gn + c1 * 8];
      rt0 = *(const u16x8*)&Mt_t[gn + c0 * 8];
      rt1 = *(const u16x8*)&Mt_t[gn + c1 * 8];
    }

    // ---- phase 1: S^T tiles for both rowsets (A shared) ----
    f32x16 cst[2][2];
#pragma unroll
    for (int rs = 0; rs < 2; rs++)
#pragma unroll
      for (int lt = 0; lt < 2; lt++) cst[rs][lt] = (f32x16)(0.f);
    __builtin_amdgcn_s_setprio(1);
#pragma unroll
    for (int kk = 0; kk < 4; kk++) {
      const int koff = ((2 * kk + hh) ^ l7) * 8;
      const bf16x8 a0 = *(const bf16x8*)&sMn[cur][l31 * 64 + koff];
      const bf16x8 a1 = *(const bf16x8*)&sMn[cur][(32 + l31) * 64 + koff];
      cst[0][0] = __builtin_amdgcn_mfma_f32_32x32x16_bf16(a0, bq[0][kk], cst[0][0], 0, 0, 0);
      cst[0][1] = __builtin_amdgcn_mfma_f32_32x32x16_bf16(a1, bq[0][kk], cst[0][1], 0, 0, 0);
      cst[1][0] = __builtin_amdgcn_mfma_f32_32x32x16_bf16(a0, bq[1][kk], cst[1][0], 0, 0, 0);
      cst[1][1] = __builtin_amdgcn_mfma_f32_32x32x16_bf16(a1, bq[1][kk], cst[1][1], 0, 0, 0);
    }
    __builtin_amdgcn_s_setprio(0);

    // ---- softmax: p = exp2(s), no max tracking (|s| <= ~1.5) ----
#pragma unroll
    for (int r = 0; r < 16; r++) {
      cst[0][0][r] = exp2_fast(cst[0][0][r]); lr0a += cst[0][0][r];
      cst[0][1][r] = exp2_fast(cst[0][1][r]); lr0b += cst[0][1][r];
      cst[1][0][r] = exp2_fast(cst[1][0][r]); lr1a += cst[1][0][r];
      cst[1][1][r] = exp2_fast(cst[1][1][r]); lr1b += cst[1][1][r];
    }

    if (rb == 7 && w == 3 && l31 == 31) {  // batch row 2047 lives in rs=1 here
#pragma unroll
      for (int lt = 0; lt < 2; lt++)
#pragma unroll
        for (int rr = 0; rr < 4; rr++)
          *(float4*)&wdump[sp * 1024 + it * 64 + 32 * lt + 8 * rr + 4 * hh] =
              make_float4(cst[1][lt][4 * rr], cst[1][lt][4 * rr + 1], cst[1][lt][4 * rr + 2],
                          cst[1][lt][4 * rr + 3]);
    }

    // pack all 8 bf16-pairs per (rs,lt)
    unsigned int pkq[2][2][8];
#pragma unroll
    for (int rs = 0; rs < 2; rs++)
#pragma unroll
      for (int lt = 0; lt < 2; lt++)
#pragma unroll
        for (int m = 0; m < 8; m++)
          pkq[rs][lt][m] = cvtpk(cst[rs][lt][2 * m], cst[rs][lt][2 * m + 1]);

    // ---- phase 2: R += P @ Mt; A-frags via permlane32_swap ----
#pragma unroll
    for (int kk = 0; kk < 4; kk++) {
      const int lt = kk >> 1, e4 = (kk & 1) * 4;
      const int koff = ((2 * kk + hh) ^ l7) * 8;
      const bf16x8 b0f = *(const bf16x8*)&sMt[cur][l31 * 64 + koff];
      const bf16x8 b1f = *(const bf16x8*)&sMt[cur][(32 + l31) * 64 + koff];
      __builtin_amdgcn_s_setprio(1);
#pragma unroll
      for (int rs = 0; rs < 2; rs++) {
        auto s0 = __builtin_amdgcn_permlane32_swap(pkq[rs][lt][e4 + 2], pkq[rs][lt][e4 + 0],
                                                   false, false);
        auto s1 = __builtin_amdgcn_permlane32_swap(pkq[rs][lt][e4 + 3], pkq[rs][lt][e4 + 1],
                                                   false, false);
        const u32x4 aw = {(unsigned int)s0[1], (unsigned int)s1[1], (unsigned int)s0[0],
                          (unsigned int)s1[0]};
        const bf16x8 afr = __builtin_bit_cast(bf16x8, aw);
        Racc[rs][0] = __builtin_amdgcn_mfma_f32_32x32x16_bf16(afr, b0f, Racc[rs][0], 0, 0, 0);
        Racc[rs][1] = __builtin_amdgcn_mfma_f32_32x32x16_bf16(afr, b1f, Racc[rs][1], 0, 0, 0);
      }
      __builtin_amdgcn_s_setprio(0);
    }

    if (it < 15) {
      const int nxt = cur ^ 1;
      *(u16x8*)&sMn[nxt][d0] = rn0; *(u16x8*)&sMn[nxt][d1] = rn1;
      *(u16x8*)&sMt[nxt][d0] = rt0; *(u16x8*)&sMt[nxt][d1] = rt1;
    }
    __syncthreads();
  }

  float lr0 = lr0a + lr0b, lr1 = lr1a + lr1b;
  lr0 += __shfl_xor(lr0, 32);
  lr1 += __shfl_xor(lr1, 32);
  if (hh == 0) {
    l_part[(size_t)(row0 + l31) * NSPLIT + sp] = lr0;
    l_part[(size_t)(row0 + 32 + l31) * NSPLIT + sp] = lr1;
  }

#pragma unroll
  for (int rs = 0; rs < 2; rs++)
#pragma unroll
    for (int dt = 0; dt < 2; dt++)
#pragma unroll
      for (int r = 0; r < 16; r++) {
        const int brow = (r & 3) + 8 * (r >> 2) + 4 * hh;
        r_bf[((size_t)(row0 + 32 * rs + brow) * NSPLIT + sp) * 64 + 32 * dt + l31] =
            f2bf_hw(Racc[rs][dt][r]);
      }
}

// ---------------- Kernel F: combine + output dot / w_read divide ----------------
__global__ __launch_bounds__(256) void k_post(const float* __restrict__ l_part,
                                              const unsigned short* __restrict__ r_bf,
                                              const float* __restrict__ h,
                                              const float* __restrict__ Wout,
                                              const float* __restrict__ bout,
                                              const float* __restrict__ wdump,
                                              float* __restrict__ out) {
  const int lane = threadIdx.x & 63, w = threadIdx.x >> 6;
  const int bx = blockIdx.x;
  if (bx < 512) {
    const int row = bx * 4 + w;
    float l = l_part[(size_t)row * NSPLIT + lane];
#pragma unroll
    for (int off = 32; off >= 1; off >>= 1) l += __shfl_xor(l, off);
    float rd = 0.f;
    for (int sp2 = 0; sp2 < NSPLIT; sp2++)
      rd += bf2f(r_bf[((size_t)row * NSPLIT + sp2) * 64 + lane]);
    rd /= l;
    float acc = Wout[CTRL + lane] * rd;
    for (int k = lane; k < CTRL; k += 64) acc += h[(size_t)row * CTRL + k] * Wout[k];
#pragma unroll
    for (int off = 32; off >= 1; off >>= 1) acc += __shfl_xor(acc, off);
    if (lane == 0) out[row] = acc + bout[0];
  } else {
    float l = l_part[(size_t)(B_SZ - 1) * NSPLIT + lane];
#pragma unroll
    for (int off = 32; off >= 1; off >>= 1) l += __shfl_xor(l, off);
    const float rl = 1.f / l;
    const int i = ((bx - 512) * 256 + threadIdx.x) * 4;
    const float4 v = *(const float4*)&wdump[i];
    *(float4*)&out[2048 + 512 + 1 + i] = make_float4(v.x * rl, v.y * rl, v.z * rl, v.w * rl);
  }
}

extern "C" void kernel_launch(void* const* d_in, const int* in_sizes, int n_in,
                              void* d_out, int out_size, void* d_ws, size_t ws_size,
                              hipStream_t stream) {
  const float* x = (const float*)d_in[0];
  const float* Wh = (const float*)d_in[1];
  const float* bh = (const float*)d_in[2];
  const float* Wg = (const float*)d_in[3];
  const float* bg = (const float*)d_in[4];
  const float* Wk = (const float*)d_in[5];
  const float* bk = (const float*)d_in[6];
  const float* M = (const float*)d_in[7];
  const float* Wout = (const float*)d_in[8];
  const float* bout = (const float*)d_in[9];
  float* out = (float*)d_out;

  float* ws = (float*)d_ws;
  float* h = ws;                                   // 1,048,576 f (4 MB)
  float* l_part = h + 1048576;                     // 131,072 f
  float* wdump = l_part + 131072;                  // 65,536 f
  unsigned short* r_bf = (unsigned short*)(wdump + 65536);  // 8,388,608 us (16 MB)
  unsigned short* kn_bf = r_bf + 8388608;          // 131,072 us
  unsigned short* Mn_t = kn_bf + 131072;           // 4,194,304 us (8 MB)
  unsigned short* Mt_t = Mn_t + 4194304;           // 4,194,304 us (8 MB)
  unsigned short* xb = Mt_t + 4194304;             // 1,048,576 us (2 MB)
  unsigned short* Wht = xb + 1048576;              // 262,144 us
  unsigned short* Wkt = Wht + 262144;              // 32,768 us  (total ~39.6 MB)

  hipLaunchKernelGGL(k_prep_all, dim3(1608), dim3(256), 0, stream,
                     x, Wh, Wk, M, xb, Wht, Wkt, Mn_t, Mt_t);
  hipLaunchKernelGGL(k_hgemm, dim3(32, 8), dim3(256), 0, stream, xb, Wht, bh, h);
  hipLaunchKernelGGL(k_readkey, dim3(65), dim3(256), 0, stream,
                     h, Wkt, bk, x, Wg, bg, kn_bf, out);
  hipLaunchKernelGGL(k_attn, dim3(NSPLIT, 8), dim3(256), 0, stream,
                     kn_bf, Mn_t, Mt_t, l_part, r_bf, wdump);
  hipLaunchKernelGGL(k_post, dim3(512 + 64), dim3(256), 0, stream,
                     l_part, r_bf, h, Wout, bout, wdump, out);
}